// Round 3
// baseline (6727.447 us; speedup 1.0000x reference)
//
#include <hip/hip_runtime.h>
#include <hip/hip_cooperative_groups.h>

namespace cg = cooperative_groups;

// fp32 everywhere (reference is jnp.float32); captions int32.
//
// Round theory: the 100-launch scan was ~47 µs/step of mostly dispatch
// machinery (~4 µs real work). Replace with ONE persistent cooperative
// kernel: 320 WGs (64 attention + 256 gates), 2 grid.sync() per step.
// fc/Gemb GEMMs: register-blocked 128x128 tile, 8x8 per thread (old
// gemm2 was 53 TF with only ~40% of VALU-busy cycles doing FMA).

static __device__ __forceinline__ float my_tanh(float x) {
    x = fminf(fmaxf(x, -15.f), 15.f);
    float e = __expf(2.f * x);
    return (e - 1.f) / (e + 1.f);
}
static __device__ __forceinline__ float my_sigmoid(float x) {
    return 1.f / (1.f + __expf(-x));
}

// ---------------------------------------------------------------------------
// Tiled fp32 transpose: out[c*R + r] = in[r*ld_in + c]   (out shape [C][R])
// ---------------------------------------------------------------------------
__global__ __launch_bounds__(256) void transpose_f32(
    const float* __restrict__ in, float* __restrict__ out,
    int R, int C, int ld_in)
{
    __shared__ float tile[32][33];
    int tc = blockIdx.x * 32;
    int tr = blockIdx.y * 32;
    int tx = threadIdx.x & 31, ty = threadIdx.x >> 5;  // 32 x 8
    #pragma unroll
    for (int i = 0; i < 4; i++) {
        int r = tr + ty + i * 8, c = tc + tx;
        tile[ty + i * 8][tx] = (r < R && c < C) ? in[(long)r * ld_in + c] : 0.f;
    }
    __syncthreads();
    #pragma unroll
    for (int i = 0; i < 4; i++) {
        int c = tc + ty + i * 8, r = tr + tx;
        if (c < C && r < R) out[(long)c * R + r] = tile[tx][ty + i * 8];
    }
}

// ---------------------------------------------------------------------------
// fp32 GEMM, 1 col/thread, 16 rows/block. Kept for att1 (N=256).
// ---------------------------------------------------------------------------
__global__ __launch_bounds__(256) void gemm_f32(
    const float* __restrict__ A, int lda,
    const float* __restrict__ B, int ldb,
    const float* __restrict__ bias,
    float* __restrict__ C, int ldc,
    int M, int N, int K)
{
    __shared__ float Asm[16 * 512];
    const int tid = threadIdx.x;
    const int n = blockIdx.x * 256 + tid;
    const bool active = n < N;
    const int nn = active ? n : (N - 1);
    const int m0 = blockIdx.y * 16;

    float acc[16];
    #pragma unroll
    for (int i = 0; i < 16; i++) acc[i] = 0.f;

    for (int kt = 0; kt < K; kt += 512) {
        for (int idx = tid; idx < 16 * 512; idx += 256) {
            int i = idx >> 9, kk = idx & 511;
            Asm[idx] = A[(long)(m0 + i) * lda + kt + kk];
        }
        __syncthreads();
        for (int k0 = 0; k0 < 512; k0 += 4) {
            float4 a4[16];
            #pragma unroll
            for (int i = 0; i < 16; i++)
                a4[i] = *(const float4*)(&Asm[i * 512 + k0]);
            #pragma unroll
            for (int j = 0; j < 4; j++) {
                float bv = B[(long)(kt + k0 + j) * ldb + nn];
                #pragma unroll
                for (int i = 0; i < 16; i++) {
                    float av = (j == 0) ? a4[i].x : (j == 1) ? a4[i].y
                             : (j == 2) ? a4[i].z : a4[i].w;
                    acc[i] = fmaf(av, bv, acc[i]);
                }
            }
        }
        __syncthreads();
    }

    if (active) {
        float bb = bias ? bias[n] : 0.f;
        #pragma unroll
        for (int i = 0; i < 16; i++)
            C[(long)(m0 + i) * ldc + n] = acc[i] + bb;
    }
}

// ---------------------------------------------------------------------------
// fp32 GEMM, 2 cols/thread, B prefetch pipeline. Kept for enc (K=2048).
// ---------------------------------------------------------------------------
__global__ __launch_bounds__(256) void gemm2_f32(
    const float* __restrict__ A, int lda,
    const float* __restrict__ B, int ldb,
    const float* __restrict__ bias,
    float* __restrict__ C, int ldc,
    int M, int N, int K)
{
    __shared__ float Asm[16 * 512];
    const int tid = threadIdx.x;
    const int n0 = blockIdx.x * 512 + tid;
    const int n1 = n0 + 256;
    const bool act0 = n0 < N, act1 = n1 < N;
    const int nn0 = act0 ? n0 : (N - 1);
    const int nn1 = act1 ? n1 : (N - 1);
    const int m0 = blockIdx.y * 16;

    float acc0[16], acc1[16];
    #pragma unroll
    for (int i = 0; i < 16; i++) { acc0[i] = 0.f; acc1[i] = 0.f; }

    for (int kt = 0; kt < K; kt += 512) {
        for (int idx = tid; idx < 16 * 512; idx += 256) {
            int i = idx >> 9, kk = idx & 511;
            Asm[idx] = A[(long)(m0 + i) * lda + kt + kk];
        }
        __syncthreads();

        float bv0[4], bv1[4];
        #pragma unroll
        for (int j = 0; j < 4; ++j) {
            bv0[j] = B[(size_t)(kt + j) * ldb + nn0];
            bv1[j] = B[(size_t)(kt + j) * ldb + nn1];
        }
        for (int k0 = 0; k0 < 512; k0 += 4) {
            float nb0[4], nb1[4];
            if (k0 + 4 < 512) {
                #pragma unroll
                for (int j = 0; j < 4; ++j) {
                    nb0[j] = B[(size_t)(kt + k0 + 4 + j) * ldb + nn0];
                    nb1[j] = B[(size_t)(kt + k0 + 4 + j) * ldb + nn1];
                }
            }
            #pragma unroll
            for (int half = 0; half < 2; ++half) {
                #pragma unroll
                for (int i = 0; i < 8; ++i) {
                    const int row = half * 8 + i;
                    const float4 a = *(const float4*)(&Asm[row * 512 + k0]);
                    acc0[row] = fmaf(a.x, bv0[0], acc0[row]);
                    acc0[row] = fmaf(a.y, bv0[1], acc0[row]);
                    acc0[row] = fmaf(a.z, bv0[2], acc0[row]);
                    acc0[row] = fmaf(a.w, bv0[3], acc0[row]);
                    acc1[row] = fmaf(a.x, bv1[0], acc1[row]);
                    acc1[row] = fmaf(a.y, bv1[1], acc1[row]);
                    acc1[row] = fmaf(a.z, bv1[2], acc1[row]);
                    acc1[row] = fmaf(a.w, bv1[3], acc1[row]);
                }
            }
            #pragma unroll
            for (int j = 0; j < 4; ++j) { bv0[j] = nb0[j]; bv1[j] = nb1[j]; }
        }
        __syncthreads();
    }

    if (act0) {
        const float bb = bias ? bias[n0] : 0.f;
        #pragma unroll
        for (int i = 0; i < 16; i++)
            C[(long)(m0 + i) * ldc + n0] = acc0[i] + bb;
    }
    if (act1) {
        const float bb = bias ? bias[n1] : 0.f;
        #pragma unroll
        for (int i = 0; i < 16; i++)
            C[(long)(m0 + i) * ldc + n1] = acc1[i] + bb;
    }
}

// ---------------------------------------------------------------------------
// Register-blocked fp32 GEMM: 128x128 C-tile, K-tiles of 16, 256 threads,
// 8x8 outputs/thread. LDS: As[16][132] (k-major, transposed store, pad 132
// keeps store conflicts at free 2-way) + Bs[16][132]. Requires K%16==0,
// N%4==0, lda/ldb%4==0. Row/col edges masked.
// ---------------------------------------------------------------------------
__global__ __launch_bounds__(256) void gemm_tile_f32(
    const float* __restrict__ A, int lda,
    const float* __restrict__ B, int ldb,
    const float* __restrict__ bias,
    float* __restrict__ C, int ldc,
    int M, int N, int K)
{
    __shared__ float As[16 * 132];
    __shared__ float Bs[16 * 132];
    const int tid = threadIdx.x;
    const int tx = tid & 15, ty = tid >> 4;
    const int rbase = blockIdx.y * 128;
    const int cbase = blockIdx.x * 128;

    float acc8[8][8];
    #pragma unroll
    for (int i = 0; i < 8; ++i)
        #pragma unroll
        for (int j = 0; j < 8; ++j) acc8[i][j] = 0.f;

    for (int kt = 0; kt < K; kt += 16) {
        // A-tile: 512 float4, 2 per thread; store transposed As[k][m]
        #pragma unroll
        for (int u = 0; u < 2; ++u) {
            const int f = tid + u * 256;
            const int m = f >> 2, kq = f & 3;
            int row = rbase + m; if (row > M - 1) row = M - 1;
            const float4 v = *(const float4*)(A + (size_t)row * lda + kt + kq * 4);
            As[(kq * 4 + 0) * 132 + m] = v.x;
            As[(kq * 4 + 1) * 132 + m] = v.y;
            As[(kq * 4 + 2) * 132 + m] = v.z;
            As[(kq * 4 + 3) * 132 + m] = v.w;
        }
        // B-tile: 512 float4, 2 per thread; natural Bs[k][n]
        #pragma unroll
        for (int u = 0; u < 2; ++u) {
            const int f = tid + u * 256;
            const int krow = f >> 5, nq = f & 31;
            int col = cbase + nq * 4; if (col > N - 4) col = N - 4;
            *(float4*)(&Bs[krow * 132 + nq * 4]) =
                *(const float4*)(B + (size_t)(kt + krow) * ldb + col);
        }
        __syncthreads();
        #pragma unroll
        for (int kk = 0; kk < 16; ++kk) {
            const float4 a0 = *(const float4*)(&As[kk * 132 + ty * 4]);
            const float4 a1 = *(const float4*)(&As[kk * 132 + 64 + ty * 4]);
            const float4 b0 = *(const float4*)(&Bs[kk * 132 + tx * 4]);
            const float4 b1 = *(const float4*)(&Bs[kk * 132 + 64 + tx * 4]);
            const float av[8] = {a0.x,a0.y,a0.z,a0.w,a1.x,a1.y,a1.z,a1.w};
            const float bv[8] = {b0.x,b0.y,b0.z,b0.w,b1.x,b1.y,b1.z,b1.w};
            #pragma unroll
            for (int i = 0; i < 8; ++i)
                #pragma unroll
                for (int j = 0; j < 8; ++j)
                    acc8[i][j] = fmaf(av[i], bv[j], acc8[i][j]);
        }
        __syncthreads();
    }

    // bias per col-group
    float4 b4[2];
    #pragma unroll
    for (int cj = 0; cj < 2; ++cj) {
        const int col = cbase + cj * 64 + tx * 4;
        if (col < N && bias) {
            b4[cj].x = bias[col]; b4[cj].y = bias[col + 1];
            b4[cj].z = bias[col + 2]; b4[cj].w = bias[col + 3];
        } else { b4[cj].x = b4[cj].y = b4[cj].z = b4[cj].w = 0.f; }
    }
    #pragma unroll
    for (int i = 0; i < 8; ++i) {
        const int row = rbase + (i >> 2) * 64 + ty * 4 + (i & 3);
        if (row >= M) continue;
        #pragma unroll
        for (int cj = 0; cj < 2; ++cj) {
            const int col = cbase + cj * 64 + tx * 4;
            if (col >= N) continue;
            float4 o;
            o.x = acc8[i][cj * 4 + 0] + b4[cj].x;
            o.y = acc8[i][cj * 4 + 1] + b4[cj].y;
            o.z = acc8[i][cj * 4 + 2] + b4[cj].z;
            o.w = acc8[i][cj * 4 + 3] + b4[cj].w;
            *(float4*)(C + (size_t)row * ldc + col) = o;
        }
    }
}

// ---------------------------------------------------------------------------
// Gather embedding rows: out[m,:] = emb[caps[m],:]  (m = b*50+t, 3200 rows)
// ---------------------------------------------------------------------------
__global__ __launch_bounds__(256) void gather_emb(
    const int* __restrict__ caps, const float* __restrict__ emb,
    float* __restrict__ out)
{
    const int m = blockIdx.x;
    const int cap = caps[m];
    const float* src = emb + (size_t)cap * 512;
    float* dst = out + (size_t)m * 512;
    dst[threadIdx.x] = src[threadIdx.x];
    dst[threadIdx.x + 256] = src[threadIdx.x + 256];
}

// ---------------------------------------------------------------------------
// Persistent cooperative scan: 320 WGs x 512 thr, 50 steps, 2 grid.sync/step.
//   WGs 0..63   : attention for batch b=wg (phase A), idle phase B.
//   WGs 64..319 : gates, (quad 0..15) x (j-slice 0..15). Phase A: gh partials
//                 (4 k-quarters x 96 gate-cols x 4 batches) into LDS.
//                 Phase B: gi partials from ctx, combine, GRU update.
// LDS 32 KB; __launch_bounds__(512,4) caps VGPR at 128 -> 2 WGs/CU
// co-residency guaranteed (320 <= 512).
// ---------------------------------------------------------------------------
__global__ __launch_bounds__(512, 4) void scan_all(
    const float* __restrict__ enc,    // [64,49,512]
    const float* __restrict__ att1,   // [64,49,256]
    const float* __restrict__ W_daT,  // [256][512]
    const float* __restrict__ b_da,   // [256]
    const float* __restrict__ W_fa,   // [256]
    const float* __restrict__ b_fa,   // [1]
    const float* __restrict__ W_ih,   // [1536][1024] natural
    const float* __restrict__ W_hh,   // [1536][512]  natural
    const float* __restrict__ b_hh,   // [1536]
    const float* __restrict__ Gemb,   // [3200][1536] (includes b_ih)
    float* __restrict__ ctx_g,        // [64][512]
    float* __restrict__ h_g,          // [64][512]
    float* __restrict__ Hbuf)         // [3200][512]
{
    cg::grid_group grid = cg::this_grid();
    __shared__ float smem[8192];

    const int tid = threadIdx.x;
    const int wg = blockIdx.x;
    const bool is_attn = wg < 64;

    // attention carve (WGs 0..63)
    float* sh     = smem;            // h: attn 512 / gates 2048
    float* a_att2 = smem + 512;      // 256
    float* a_part = smem + 768;      // 512
    float* a_red  = smem + 1280;     // 392
    float* a_s    = smem + 1680;     // 64
    // gates carve (WGs 64..319)
    float* g_c   = smem + 2048;      // 2048
    float* g_ghp = smem + 4096;      // 384*4
    float* g_gip = smem + 5632;      // 384*4
    float* g_ghc = smem + 7168;      // 96*4
    float* g_gic = smem + 7552;      // 96*4

    const int b   = wg;              // attn batch
    const int gwg = wg - 64;
    const int quad = gwg >> 4, sl = gwg & 15;
    const int b0 = quad * 4;

    for (int t = 0; t < 50; ++t) {
        // ================= phase A =================
        if (is_attn) {
            sh[tid] = (t == 0) ? 0.f : h_g[(size_t)b * 512 + tid];
            __syncthreads();
            // att2 partials: j = tid>>1, k-half = tid&1
            {
                const int j = tid >> 1, kh2 = tid & 1;
                const float4* w4 = (const float4*)(W_daT + (size_t)j * 512 + kh2 * 256);
                const float* hh = sh + kh2 * 256;
                float a = 0.f;
                #pragma unroll 8
                for (int kq = 0; kq < 64; ++kq) {
                    const float4 w = w4[kq];
                    const float4 x = *(const float4*)(hh + kq * 4);
                    a = fmaf(x.x, w.x, a); a = fmaf(x.y, w.y, a);
                    a = fmaf(x.z, w.z, a); a = fmaf(x.w, w.w, a);
                }
                a_part[tid] = a;
            }
            __syncthreads();
            if (tid < 256)
                a_att2[tid] = a_part[2 * tid] + a_part[2 * tid + 1] + b_da[tid];
            __syncthreads();
            // scores: 49 l x 8 chunks of 32 j
            if (tid < 392) {
                const int l = tid >> 3, ch = tid & 7;
                const float4* a4 =
                    (const float4*)(att1 + ((size_t)b * 49 + l) * 256 + ch * 32);
                const float* at2 = a_att2 + ch * 32;
                const float* wf = W_fa + ch * 32;
                float s = 0.f;
                #pragma unroll
                for (int i = 0; i < 8; ++i) {
                    const float4 v = a4[i];
                    s += my_tanh(v.x + at2[i * 4 + 0]) * wf[i * 4 + 0];
                    s += my_tanh(v.y + at2[i * 4 + 1]) * wf[i * 4 + 1];
                    s += my_tanh(v.z + at2[i * 4 + 2]) * wf[i * 4 + 2];
                    s += my_tanh(v.w + at2[i * 4 + 3]) * wf[i * 4 + 3];
                }
                a_red[tid] = s;
            }
            __syncthreads();
            if (tid < 49) {
                const float* r = a_red + tid * 8;
                a_s[tid] = r[0] + r[1] + r[2] + r[3] + r[4] + r[5] + r[6] + r[7]
                         + b_fa[0];
            }
            __syncthreads();
            // softmax over L=49, wave 0
            if (tid < 64) {
                const float v = (tid < 49) ? a_s[tid] : -1e30f;
                float m = v;
                #pragma unroll
                for (int o = 32; o; o >>= 1) m = fmaxf(m, __shfl_xor(m, o));
                const float e = (tid < 49) ? __expf(v - m) : 0.f;
                float su = e;
                #pragma unroll
                for (int o = 32; o; o >>= 1) su += __shfl_xor(su, o);
                if (tid < 49) a_s[tid] = e / su;
            }
            __syncthreads();
            // context -> ctx_g
            {
                const float* e0 = enc + (size_t)b * 49 * 512 + tid;
                float c = 0.f;
                #pragma unroll
                for (int l = 0; l < 49; ++l)
                    c = fmaf(a_s[l], e0[(size_t)l * 512], c);
                ctx_g[(size_t)b * 512 + tid] = c;
            }
        } else {
            // gates phase A: stage h, gh partials
            for (int i = tid; i < 2048; i += 512)
                sh[i] = (t == 0) ? 0.f : h_g[(size_t)b0 * 512 + i];
            __syncthreads();
            if (tid < 384) {
                const int cc = tid % 96, kh = tid / 96;   // 96 cols x 4 k-quarters
                const int gate = cc >> 5, jj = cc & 31;
                const int n = gate * 512 + sl * 32 + jj;
                const float4* w4 = (const float4*)(W_hh + (size_t)n * 512 + kh * 128);
                const float* xb = sh + kh * 128;
                float a0 = 0.f, a1 = 0.f, a2 = 0.f, a3 = 0.f;
                #pragma unroll 8
                for (int kq = 0; kq < 32; ++kq) {
                    const float4 w = w4[kq];
                    const int k4 = kq * 4;
                    const float4 x0 = *(const float4*)(xb + k4);
                    const float4 x1 = *(const float4*)(xb + 512 + k4);
                    const float4 x2 = *(const float4*)(xb + 1024 + k4);
                    const float4 x3 = *(const float4*)(xb + 1536 + k4);
                    a0 = fmaf(x0.x, w.x, a0); a0 = fmaf(x0.y, w.y, a0);
                    a0 = fmaf(x0.z, w.z, a0); a0 = fmaf(x0.w, w.w, a0);
                    a1 = fmaf(x1.x, w.x, a1); a1 = fmaf(x1.y, w.y, a1);
                    a1 = fmaf(x1.z, w.z, a1); a1 = fmaf(x1.w, w.w, a1);
                    a2 = fmaf(x2.x, w.x, a2); a2 = fmaf(x2.y, w.y, a2);
                    a2 = fmaf(x2.z, w.z, a2); a2 = fmaf(x2.w, w.w, a2);
                    a3 = fmaf(x3.x, w.x, a3); a3 = fmaf(x3.y, w.y, a3);
                    a3 = fmaf(x3.z, w.z, a3); a3 = fmaf(x3.w, w.w, a3);
                }
                const int base = (kh * 96 + cc) * 4;
                g_ghp[base + 0] = a0; g_ghp[base + 1] = a1;
                g_ghp[base + 2] = a2; g_ghp[base + 3] = a3;
            }
        }
        grid.sync();   // ctx ready; gh partials done
        // ================= phase B =================
        if (!is_attn) {
            for (int i = tid; i < 2048; i += 512)
                g_c[i] = ctx_g[(size_t)b0 * 512 + i];
            __syncthreads();
            if (tid < 384) {
                const int cc = tid % 96, kh = tid / 96;
                const int gate = cc >> 5, jj = cc & 31;
                const int n = gate * 512 + sl * 32 + jj;
                const float4* w4 =
                    (const float4*)(W_ih + (size_t)n * 1024 + 512 + kh * 128);
                const float* xb = g_c + kh * 128;
                float a0 = 0.f, a1 = 0.f, a2 = 0.f, a3 = 0.f;
                #pragma unroll 8
                for (int kq = 0; kq < 32; ++kq) {
                    const float4 w = w4[kq];
                    const int k4 = kq * 4;
                    const float4 x0 = *(const float4*)(xb + k4);
                    const float4 x1 = *(const float4*)(xb + 512 + k4);
                    const float4 x2 = *(const float4*)(xb + 1024 + k4);
                    const float4 x3 = *(const float4*)(xb + 1536 + k4);
                    a0 = fmaf(x0.x, w.x, a0); a0 = fmaf(x0.y, w.y, a0);
                    a0 = fmaf(x0.z, w.z, a0); a0 = fmaf(x0.w, w.w, a0);
                    a1 = fmaf(x1.x, w.x, a1); a1 = fmaf(x1.y, w.y, a1);
                    a1 = fmaf(x1.z, w.z, a1); a1 = fmaf(x1.w, w.w, a1);
                    a2 = fmaf(x2.x, w.x, a2); a2 = fmaf(x2.y, w.y, a2);
                    a2 = fmaf(x2.z, w.z, a2); a2 = fmaf(x2.w, w.w, a2);
                    a3 = fmaf(x3.x, w.x, a3); a3 = fmaf(x3.y, w.y, a3);
                    a3 = fmaf(x3.z, w.z, a3); a3 = fmaf(x3.w, w.w, a3);
                }
                const int base = (kh * 96 + cc) * 4;
                g_gip[base + 0] = a0; g_gip[base + 1] = a1;
                g_gip[base + 2] = a2; g_gip[base + 3] = a3;
            }
            __syncthreads();
            if (tid < 96) {
                const int cc = tid;
                const int gate = cc >> 5, jj = cc & 31;
                const int n = gate * 512 + sl * 32 + jj;
                const float bh = b_hh[n];
                #pragma unroll
                for (int bb = 0; bb < 4; ++bb) {
                    const float gh = g_ghp[cc * 4 + bb] + g_ghp[(96 + cc) * 4 + bb]
                                   + g_ghp[(192 + cc) * 4 + bb]
                                   + g_ghp[(288 + cc) * 4 + bb] + bh;
                    const float gi = g_gip[cc * 4 + bb] + g_gip[(96 + cc) * 4 + bb]
                                   + g_gip[(192 + cc) * 4 + bb]
                                   + g_gip[(288 + cc) * 4 + bb]
                                   + Gemb[((size_t)(b0 + bb) * 50 + t) * 1536 + n];
                    g_ghc[cc * 4 + bb] = gh;
                    g_gic[cc * 4 + bb] = gi;
                }
            }
            __syncthreads();
            if (tid < 128) {
                const int bb = tid >> 5, jj = tid & 31;
                const int j = sl * 32 + jj;
                const float ghr = g_ghc[jj * 4 + bb];
                const float ghz = g_ghc[(32 + jj) * 4 + bb];
                const float ghn = g_ghc[(64 + jj) * 4 + bb];
                const float gir = g_gic[jj * 4 + bb];
                const float giz = g_gic[(32 + jj) * 4 + bb];
                const float gin = g_gic[(64 + jj) * 4 + bb];
                const float r  = my_sigmoid(gir + ghr);
                const float z  = my_sigmoid(giz + ghz);
                const float nn = my_tanh(gin + r * ghn);
                const float hnew = (1.f - z) * nn + z * sh[bb * 512 + j];
                h_g[(size_t)(b0 + bb) * 512 + j] = hnew;
                Hbuf[((size_t)(b0 + bb) * 50 + t) * 512 + j] = hnew;
            }
        }
        grid.sync();   // h updated
    }
}

// ---------------------------------------------------------------------------
// Fallback per-step kernels (used only if cooperative launch is rejected).
// ---------------------------------------------------------------------------
__global__ __launch_bounds__(512) void attn_step(
    const int t,
    const float* __restrict__ enc, const float* __restrict__ att1,
    const float* __restrict__ W_daT, const float* __restrict__ b_da,
    const float* __restrict__ W_fa, const float* __restrict__ b_fa,
    const float* __restrict__ h_g, float* __restrict__ ctx_g)
{
    __shared__ float sh_h[512];
    __shared__ float sh_att2[256];
    __shared__ float sh_part[512];
    __shared__ float sh_red[49 * 8];
    __shared__ float sh_s[64];

    const int tid = threadIdx.x;
    const int b = blockIdx.x;

    sh_h[tid] = (t == 0) ? 0.f : h_g[(size_t)b * 512 + tid];
    __syncthreads();
    {
        const int j = tid >> 1, kh = tid & 1;
        const float4* w4 = (const float4*)(W_daT + (size_t)j * 512 + kh * 256);
        const float* hh = sh_h + kh * 256;
        float a = 0.f;
        #pragma unroll 8
        for (int kq = 0; kq < 64; ++kq) {
            const float4 w = w4[kq];
            const float4 x = *(const float4*)(hh + kq * 4);
            a = fmaf(x.x, w.x, a); a = fmaf(x.y, w.y, a);
            a = fmaf(x.z, w.z, a); a = fmaf(x.w, w.w, a);
        }
        sh_part[tid] = a;
    }
    __syncthreads();
    if (tid < 256) sh_att2[tid] = sh_part[tid * 2] + sh_part[tid * 2 + 1] + b_da[tid];
    __syncthreads();
    if (tid < 392) {
        const int l = tid >> 3, ch = tid & 7;
        const float4* a4 = (const float4*)(att1 + ((size_t)b * 49 + l) * 256 + ch * 32);
        const float* at2 = sh_att2 + ch * 32;
        const float* wf = W_fa + ch * 32;
        float s = 0.f;
        #pragma unroll
        for (int i = 0; i < 8; ++i) {
            const float4 v = a4[i];
            s += my_tanh(v.x + at2[i * 4 + 0]) * wf[i * 4 + 0];
            s += my_tanh(v.y + at2[i * 4 + 1]) * wf[i * 4 + 1];
            s += my_tanh(v.z + at2[i * 4 + 2]) * wf[i * 4 + 2];
            s += my_tanh(v.w + at2[i * 4 + 3]) * wf[i * 4 + 3];
        }
        sh_red[tid] = s;
    }
    __syncthreads();
    if (tid < 49) {
        const float* r = sh_red + tid * 8;
        sh_s[tid] = r[0] + r[1] + r[2] + r[3] + r[4] + r[5] + r[6] + r[7] + b_fa[0];
    }
    __syncthreads();
    if (tid < 64) {
        const float v = (tid < 49) ? sh_s[tid] : -1e30f;
        float m = v;
        #pragma unroll
        for (int o = 32; o; o >>= 1) m = fmaxf(m, __shfl_xor(m, o));
        const float e = (tid < 49) ? __expf(v - m) : 0.f;
        float su = e;
        #pragma unroll
        for (int o = 32; o; o >>= 1) su += __shfl_xor(su, o);
        if (tid < 49) sh_s[tid] = e / su;
    }
    __syncthreads();
    {
        const float* e0 = enc + (size_t)b * 49 * 512 + tid;
        float c = 0.f;
        #pragma unroll
        for (int l = 0; l < 49; ++l) c = fmaf(sh_s[l], e0[(size_t)l * 512], c);
        ctx_g[(size_t)b * 512 + tid] = c;
    }
}

__global__ __launch_bounds__(512) void gates_step(
    const int t,
    const float* __restrict__ W_ih, const float* __restrict__ W_hh,
    const float* __restrict__ b_hh, const float* __restrict__ Gemb,
    const float* __restrict__ ctx_g, float* __restrict__ h_g,
    float* __restrict__ Hbuf)
{
    __shared__ float sh_h[4 * 512];
    __shared__ float sh_c[4 * 512];
    __shared__ float sh_part[384 * 4];
    __shared__ float sh_gate[192 * 4];

    const int tid = threadIdx.x;
    const int g16 = blockIdx.x >> 4;
    const int sl  = blockIdx.x & 15;
    const int b0 = g16 * 4;

    for (int i = tid; i < 2048; i += 512) {
        sh_h[i] = (t == 0) ? 0.f : h_g[(size_t)b0 * 512 + i];
        sh_c[i] = ctx_g[(size_t)b0 * 512 + i];
    }
    __syncthreads();

    if (tid < 384) {
        const int colL = (tid < 192) ? tid : tid - 192;
        const int kh   = (tid < 192) ? 0 : 1;
        const bool is_gi = colL >= 96;
        const int cc = is_gi ? colL - 96 : colL;
        const int gate = cc >> 5, jj = cc & 31;
        const int n = gate * 512 + sl * 32 + jj;
        const float4* w4 = is_gi
            ? (const float4*)(W_ih + (size_t)n * 1024 + 512 + kh * 256)
            : (const float4*)(W_hh + (size_t)n * 512 + kh * 256);
        const float* xb = (is_gi ? sh_c : sh_h) + kh * 256;
        float a0 = 0.f, a1 = 0.f, a2 = 0.f, a3 = 0.f;
        #pragma unroll 8
        for (int kq = 0; kq < 64; ++kq) {
            const float4 w = w4[kq];
            const int k4 = kq * 4;
            const float4 x0 = *(const float4*)(xb + k4);
            const float4 x1 = *(const float4*)(xb + 512 + k4);
            const float4 x2 = *(const float4*)(xb + 1024 + k4);
            const float4 x3 = *(const float4*)(xb + 1536 + k4);
            a0 = fmaf(x0.x, w.x, a0); a0 = fmaf(x0.y, w.y, a0);
            a0 = fmaf(x0.z, w.z, a0); a0 = fmaf(x0.w, w.w, a0);
            a1 = fmaf(x1.x, w.x, a1); a1 = fmaf(x1.y, w.y, a1);
            a1 = fmaf(x1.z, w.z, a1); a1 = fmaf(x1.w, w.w, a1);
            a2 = fmaf(x2.x, w.x, a2); a2 = fmaf(x2.y, w.y, a2);
            a2 = fmaf(x2.z, w.z, a2); a2 = fmaf(x2.w, w.w, a2);
            a3 = fmaf(x3.x, w.x, a3); a3 = fmaf(x3.y, w.y, a3);
            a3 = fmaf(x3.z, w.z, a3); a3 = fmaf(x3.w, w.w, a3);
        }
        const int base = (kh * 192 + colL) * 4;
        sh_part[base + 0] = a0; sh_part[base + 1] = a1;
        sh_part[base + 2] = a2; sh_part[base + 3] = a3;
    }
    __syncthreads();

    if (tid < 192) {
        const bool is_gi = tid >= 96;
        const int cc = is_gi ? tid - 96 : tid;
        const int gate = cc >> 5, jj = cc & 31;
        const int n = gate * 512 + sl * 32 + jj;
        #pragma unroll
        for (int bb = 0; bb < 4; ++bb) {
            float v = sh_part[tid * 4 + bb] + sh_part[(192 + tid) * 4 + bb];
            if (is_gi) v += Gemb[((size_t)(b0 + bb) * 50 + t) * 1536 + n];
            else       v += b_hh[n];
            sh_gate[tid * 4 + bb] = v;
        }
    }
    __syncthreads();

    if (tid < 128) {
        const int bb = tid >> 5, jj = tid & 31;
        const int j = sl * 32 + jj;
        const float ghr = sh_gate[(jj) * 4 + bb];
        const float ghz = sh_gate[(32 + jj) * 4 + bb];
        const float ghn = sh_gate[(64 + jj) * 4 + bb];
        const float gir = sh_gate[(96 + jj) * 4 + bb];
        const float giz = sh_gate[(96 + 32 + jj) * 4 + bb];
        const float gin = sh_gate[(96 + 64 + jj) * 4 + bb];
        const float r  = my_sigmoid(gir + ghr);
        const float z  = my_sigmoid(giz + ghz);
        const float nn = my_tanh(gin + r * ghn);
        const float hnew = (1.f - z) * nn + z * sh_h[bb * 512 + j];
        h_g[(size_t)(b0 + bb) * 512 + j] = hnew;
        Hbuf[((size_t)(b0 + bb) * 50 + t) * 512 + j] = hnew;
    }
}

// ---------------------------------------------------------------------------
extern "C" void kernel_launch(void* const* d_in, const int* in_sizes, int n_in,
                              void* d_out, int out_size, void* d_ws, size_t ws_size,
                              hipStream_t stream) {
    const float* spatial = (const float*)d_in[0];
    const int*   captions= (const int*)d_in[1];
    const float* W_feat  = (const float*)d_in[2];
    const float* b_feat  = (const float*)d_in[3];
    const float* W_ea    = (const float*)d_in[4];
    const float* b_ea    = (const float*)d_in[5];
    const float* W_da    = (const float*)d_in[6];
    const float* b_da    = (const float*)d_in[7];
    const float* W_fa    = (const float*)d_in[8];
    const float* b_fa    = (const float*)d_in[9];
    const float* emb     = (const float*)d_in[10];
    const float* W_ih    = (const float*)d_in[11];
    const float* W_hh    = (const float*)d_in[12];
    const float* b_ih    = (const float*)d_in[13];
    const float* b_hh    = (const float*)d_in[14];
    const float* W_fc    = (const float*)d_in[15];
    const float* b_fc    = (const float*)d_in[16];
    float* out = (float*)d_out;

    // Workspace layout (same as round 2). Embt aliases Hbuf (consumed by the
    // Gemb GEMM before the scan writes Hbuf; same-stream ordering).
    char* ws = (char*)d_ws;
    float* Wt_ih = (float*)ws; ws += (size_t)1024 * 1536 * 4;   //  6,291,456
    float* W_daT = (float*)ws; ws += (size_t)256 * 512 * 4;     //    524,288
    float* enc   = (float*)ws; ws += (size_t)3136 * 512 * 4;    //  6,422,528
    float* att1  = (float*)ws; ws += (size_t)3136 * 256 * 4;    //  3,211,264
    float* Hbuf  = (float*)ws; ws += (size_t)3200 * 512 * 4;    //  6,553,600
    float* Gemb  = (float*)ws; ws += (size_t)3200 * 1536 * 4;   // 19,660,800
    float* h_g   = (float*)ws; ws += (size_t)64 * 512 * 4;      //    131,072
    float* ctx_g = (float*)ws; ws += (size_t)64 * 512 * 4;      //    131,072
    float* Embt  = Hbuf;
    const size_t NEED = 6291456ull + 524288 + 6422528 + 3211264 + 6553600
                      + 19660800 + 131072 + 131072;
    if (ws_size < NEED) return;

    dim3 blk(256);
    // Wt_ih[1024][1536] = W_ih^T (emb part = rows 0..511, used by Gemb GEMM)
    transpose_f32<<<dim3(32, 48), blk, 0, stream>>>(W_ih, Wt_ih, 1536, 1024, 1024);
    // W_daT[256][512] = W_da^T (attention row streaming)
    transpose_f32<<<dim3(8, 16), blk, 0, stream>>>(W_da, W_daT, 512, 256, 256);

    // Embt[m,:] = emb[captions[m],:]          [3200,512]
    gather_emb<<<dim3(3200), blk, 0, stream>>>(captions, emb, Embt);

    // enc = spatial @ W_feat + b_feat         [3136,512]
    gemm2_f32<<<dim3(1, 196), blk, 0, stream>>>(spatial, 2048, W_feat, 512, b_feat,
                                                enc, 512, 3136, 512, 2048);
    // att1 = enc @ W_ea + b_ea                [3136,256]
    gemm_f32<<<dim3(1, 196), blk, 0, stream>>>(enc, 512, W_ea, 256, b_ea,
                                               att1, 256, 3136, 256, 512);
    // Gemb = Embt @ Wt_ih[0:512,:] + b_ih     [3200,1536]
    gemm_tile_f32<<<dim3(12, 25), blk, 0, stream>>>(Embt, 512, Wt_ih, 1536, b_ih,
                                                    Gemb, 1536, 3200, 1536, 512);

    // recurrent scan: one cooperative dispatch (fallback: per-step launches)
    {
        void* args[] = { (void*)&enc, (void*)&att1, (void*)&W_daT, (void*)&b_da,
                         (void*)&W_fa, (void*)&b_fa, (void*)&W_ih, (void*)&W_hh,
                         (void*)&b_hh, (void*)&Gemb, (void*)&ctx_g, (void*)&h_g,
                         (void*)&Hbuf };
        hipError_t cerr = hipLaunchCooperativeKernel(
            (const void*)scan_all, dim3(320), dim3(512), args, 0, stream);
        if (cerr != hipSuccess) {
            for (int t = 0; t < 50; ++t) {
                attn_step<<<dim3(64), dim3(512), 0, stream>>>(
                    t, enc, att1, W_daT, b_da, W_fa, b_fa, h_g, ctx_g);
                gates_step<<<dim3(256), dim3(512), 0, stream>>>(
                    t, W_ih, W_hh, b_hh, Gemb, ctx_g, h_g, Hbuf);
            }
        }
    }

    // logits = Hbuf @ W_fc + b_fc -> d_out    [3200,10000]
    gemm_tile_f32<<<dim3(79, 25), blk, 0, stream>>>(Hbuf, 512, W_fc, 10000, b_fc,
                                                    out, 10000, 3200, 10000, 512);
}

// Round 4
// 4518.646 us; speedup vs baseline: 1.4888x; 1.4888x over previous
//
#include <hip/hip_runtime.h>

// fp32 everywhere (reference is jnp.float32); captions int32.
//
// Round theory: grid.sync() costs ~25 µs on MI355X (device-scope L2
// writeback/invalidate for XCD coherence) -> cooperative scan was 2.4x
// WORSE than per-step launches. Key fix: the recurrence is independent
// per batch, so ONE WG per batch runs all 50 steps in ONE plain launch
// with zero syncs. The ctx@W_ihc GEMM is reassociated out of the scan:
//   gi_ctx[b,n] = sum_l alpha[l] * P[b,l,n],  P = enc @ W_ihc^T
// (P precomputed; P and Gemb live in d_out scratch, dead before fc
// overwrites it). Scan streams only Wt_hh (L2-resident) + P[b] + att1[b].

static __device__ __forceinline__ float my_tanh(float x) {
    x = fminf(fmaxf(x, -15.f), 15.f);
    float e = __expf(2.f * x);
    return (e - 1.f) / (e + 1.f);
}
static __device__ __forceinline__ float my_sigmoid(float x) {
    return 1.f / (1.f + __expf(-x));
}

// ---------------------------------------------------------------------------
// Tiled fp32 transpose: out[c*R + r] = in[r*ld_in + c]   (out shape [C][R])
// ---------------------------------------------------------------------------
__global__ __launch_bounds__(256) void transpose_f32(
    const float* __restrict__ in, float* __restrict__ out,
    int R, int C, int ld_in)
{
    __shared__ float tile[32][33];
    int tc = blockIdx.x * 32;
    int tr = blockIdx.y * 32;
    int tx = threadIdx.x & 31, ty = threadIdx.x >> 5;  // 32 x 8
    #pragma unroll
    for (int i = 0; i < 4; i++) {
        int r = tr + ty + i * 8, c = tc + tx;
        tile[ty + i * 8][tx] = (r < R && c < C) ? in[(long)r * ld_in + c] : 0.f;
    }
    __syncthreads();
    #pragma unroll
    for (int i = 0; i < 4; i++) {
        int c = tc + ty + i * 8, r = tr + tx;
        if (c < C && r < R) out[(long)c * R + r] = tile[tx][ty + i * 8];
    }
}

// ---------------------------------------------------------------------------
// fp32 GEMM, 1 col/thread, 16 rows/block. Used for att1 (N=256).
// ---------------------------------------------------------------------------
__global__ __launch_bounds__(256) void gemm_f32(
    const float* __restrict__ A, int lda,
    const float* __restrict__ B, int ldb,
    const float* __restrict__ bias,
    float* __restrict__ C, int ldc,
    int M, int N, int K)
{
    __shared__ float Asm[16 * 512];
    const int tid = threadIdx.x;
    const int n = blockIdx.x * 256 + tid;
    const bool active = n < N;
    const int nn = active ? n : (N - 1);
    const int m0 = blockIdx.y * 16;

    float acc[16];
    #pragma unroll
    for (int i = 0; i < 16; i++) acc[i] = 0.f;

    for (int kt = 0; kt < K; kt += 512) {
        for (int idx = tid; idx < 16 * 512; idx += 256) {
            int i = idx >> 9, kk = idx & 511;
            Asm[idx] = A[(long)(m0 + i) * lda + kt + kk];
        }
        __syncthreads();
        for (int k0 = 0; k0 < 512; k0 += 4) {
            float4 a4[16];
            #pragma unroll
            for (int i = 0; i < 16; i++)
                a4[i] = *(const float4*)(&Asm[i * 512 + k0]);
            #pragma unroll
            for (int j = 0; j < 4; j++) {
                float bv = B[(long)(kt + k0 + j) * ldb + nn];
                #pragma unroll
                for (int i = 0; i < 16; i++) {
                    float av = (j == 0) ? a4[i].x : (j == 1) ? a4[i].y
                             : (j == 2) ? a4[i].z : a4[i].w;
                    acc[i] = fmaf(av, bv, acc[i]);
                }
            }
        }
        __syncthreads();
    }

    if (active) {
        float bb = bias ? bias[n] : 0.f;
        #pragma unroll
        for (int i = 0; i < 16; i++)
            C[(long)(m0 + i) * ldc + n] = acc[i] + bb;
    }
}

// ---------------------------------------------------------------------------
// fp32 GEMM, 2 cols/thread, B prefetch pipeline. Used for enc (K=2048).
// ---------------------------------------------------------------------------
__global__ __launch_bounds__(256) void gemm2_f32(
    const float* __restrict__ A, int lda,
    const float* __restrict__ B, int ldb,
    const float* __restrict__ bias,
    float* __restrict__ C, int ldc,
    int M, int N, int K)
{
    __shared__ float Asm[16 * 512];
    const int tid = threadIdx.x;
    const int n0 = blockIdx.x * 512 + tid;
    const int n1 = n0 + 256;
    const bool act0 = n0 < N, act1 = n1 < N;
    const int nn0 = act0 ? n0 : (N - 1);
    const int nn1 = act1 ? n1 : (N - 1);
    const int m0 = blockIdx.y * 16;

    float acc0[16], acc1[16];
    #pragma unroll
    for (int i = 0; i < 16; i++) { acc0[i] = 0.f; acc1[i] = 0.f; }

    for (int kt = 0; kt < K; kt += 512) {
        for (int idx = tid; idx < 16 * 512; idx += 256) {
            int i = idx >> 9, kk = idx & 511;
            Asm[idx] = A[(long)(m0 + i) * lda + kt + kk];
        }
        __syncthreads();

        float bv0[4], bv1[4];
        #pragma unroll
        for (int j = 0; j < 4; ++j) {
            bv0[j] = B[(size_t)(kt + j) * ldb + nn0];
            bv1[j] = B[(size_t)(kt + j) * ldb + nn1];
        }
        for (int k0 = 0; k0 < 512; k0 += 4) {
            float nb0[4], nb1[4];
            if (k0 + 4 < 512) {
                #pragma unroll
                for (int j = 0; j < 4; ++j) {
                    nb0[j] = B[(size_t)(kt + k0 + 4 + j) * ldb + nn0];
                    nb1[j] = B[(size_t)(kt + k0 + 4 + j) * ldb + nn1];
                }
            }
            #pragma unroll
            for (int half = 0; half < 2; ++half) {
                #pragma unroll
                for (int i = 0; i < 8; ++i) {
                    const int row = half * 8 + i;
                    const float4 a = *(const float4*)(&Asm[row * 512 + k0]);
                    acc0[row] = fmaf(a.x, bv0[0], acc0[row]);
                    acc0[row] = fmaf(a.y, bv0[1], acc0[row]);
                    acc0[row] = fmaf(a.z, bv0[2], acc0[row]);
                    acc0[row] = fmaf(a.w, bv0[3], acc0[row]);
                    acc1[row] = fmaf(a.x, bv1[0], acc1[row]);
                    acc1[row] = fmaf(a.y, bv1[1], acc1[row]);
                    acc1[row] = fmaf(a.z, bv1[2], acc1[row]);
                    acc1[row] = fmaf(a.w, bv1[3], acc1[row]);
                }
            }
            #pragma unroll
            for (int j = 0; j < 4; ++j) { bv0[j] = nb0[j]; bv1[j] = nb1[j]; }
        }
        __syncthreads();
    }

    if (act0) {
        const float bb = bias ? bias[n0] : 0.f;
        #pragma unroll
        for (int i = 0; i < 16; i++)
            C[(long)(m0 + i) * ldc + n0] = acc0[i] + bb;
    }
    if (act1) {
        const float bb = bias ? bias[n1] : 0.f;
        #pragma unroll
        for (int i = 0; i < 16; i++)
            C[(long)(m0 + i) * ldc + n1] = acc1[i] + bb;
    }
}

// ---------------------------------------------------------------------------
// Register-blocked fp32 GEMM: 128x128 C-tile, K-tiles of 16, 256 threads,
// 8x8 outputs/thread. Used for Gemb, P, fc. Requires K%16==0, N%4==0.
// ---------------------------------------------------------------------------
__global__ __launch_bounds__(256) void gemm_tile_f32(
    const float* __restrict__ A, int lda,
    const float* __restrict__ B, int ldb,
    const float* __restrict__ bias,
    float* __restrict__ C, int ldc,
    int M, int N, int K)
{
    __shared__ float As[16 * 132];
    __shared__ float Bs[16 * 132];
    const int tid = threadIdx.x;
    const int tx = tid & 15, ty = tid >> 4;
    const int rbase = blockIdx.y * 128;
    const int cbase = blockIdx.x * 128;

    float acc8[8][8];
    #pragma unroll
    for (int i = 0; i < 8; ++i)
        #pragma unroll
        for (int j = 0; j < 8; ++j) acc8[i][j] = 0.f;

    for (int kt = 0; kt < K; kt += 16) {
        #pragma unroll
        for (int u = 0; u < 2; ++u) {
            const int f = tid + u * 256;
            const int m = f >> 2, kq = f & 3;
            int row = rbase + m; if (row > M - 1) row = M - 1;
            const float4 v = *(const float4*)(A + (size_t)row * lda + kt + kq * 4);
            As[(kq * 4 + 0) * 132 + m] = v.x;
            As[(kq * 4 + 1) * 132 + m] = v.y;
            As[(kq * 4 + 2) * 132 + m] = v.z;
            As[(kq * 4 + 3) * 132 + m] = v.w;
        }
        #pragma unroll
        for (int u = 0; u < 2; ++u) {
            const int f = tid + u * 256;
            const int krow = f >> 5, nq = f & 31;
            int col = cbase + nq * 4; if (col > N - 4) col = N - 4;
            *(float4*)(&Bs[krow * 132 + nq * 4]) =
                *(const float4*)(B + (size_t)(kt + krow) * ldb + col);
        }
        __syncthreads();
        #pragma unroll
        for (int kk = 0; kk < 16; ++kk) {
            const float4 a0 = *(const float4*)(&As[kk * 132 + ty * 4]);
            const float4 a1 = *(const float4*)(&As[kk * 132 + 64 + ty * 4]);
            const float4 b0 = *(const float4*)(&Bs[kk * 132 + tx * 4]);
            const float4 b1 = *(const float4*)(&Bs[kk * 132 + 64 + tx * 4]);
            const float av[8] = {a0.x,a0.y,a0.z,a0.w,a1.x,a1.y,a1.z,a1.w};
            const float bv[8] = {b0.x,b0.y,b0.z,b0.w,b1.x,b1.y,b1.z,b1.w};
            #pragma unroll
            for (int i = 0; i < 8; ++i)
                #pragma unroll
                for (int j = 0; j < 8; ++j)
                    acc8[i][j] = fmaf(av[i], bv[j], acc8[i][j]);
        }
        __syncthreads();
    }

    float4 b4[2];
    #pragma unroll
    for (int cj = 0; cj < 2; ++cj) {
        const int col = cbase + cj * 64 + tx * 4;
        if (col < N && bias) {
            b4[cj].x = bias[col]; b4[cj].y = bias[col + 1];
            b4[cj].z = bias[col + 2]; b4[cj].w = bias[col + 3];
        } else { b4[cj].x = b4[cj].y = b4[cj].z = b4[cj].w = 0.f; }
    }
    #pragma unroll
    for (int i = 0; i < 8; ++i) {
        const int row = rbase + (i >> 2) * 64 + ty * 4 + (i & 3);
        if (row >= M) continue;
        #pragma unroll
        for (int cj = 0; cj < 2; ++cj) {
            const int col = cbase + cj * 64 + tx * 4;
            if (col >= N) continue;
            float4 o;
            o.x = acc8[i][cj * 4 + 0] + b4[cj].x;
            o.y = acc8[i][cj * 4 + 1] + b4[cj].y;
            o.z = acc8[i][cj * 4 + 2] + b4[cj].z;
            o.w = acc8[i][cj * 4 + 3] + b4[cj].w;
            *(float4*)(C + (size_t)row * ldc + col) = o;
        }
    }
}

// ---------------------------------------------------------------------------
// Gather embedding rows: out[m,:] = emb[caps[m],:]  (m = b*50+t, 3200 rows)
// ---------------------------------------------------------------------------
__global__ __launch_bounds__(256) void gather_emb(
    const int* __restrict__ caps, const float* __restrict__ emb,
    float* __restrict__ out)
{
    const int m = blockIdx.x;
    const int cap = caps[m];
    const float* src = emb + (size_t)cap * 512;
    float* dst = out + (size_t)m * 512;
    dst[threadIdx.x] = src[threadIdx.x];
    dst[threadIdx.x + 256] = src[threadIdx.x + 256];
}

// ---------------------------------------------------------------------------
// Persistent per-batch scan: 64 WGs x 512 thr, ONE plain launch, no global
// sync (batches are independent). Per step, per WG (batch b):
//   att2 = h @ W_da + b_da            (W_daT row-stream, float4)
//   scores/softmax -> alpha[49]       (att1[b] from L2, wave-0 softmax)
//   gh partials: thread (jq=tid&127, kq=tid>>7) owns 12 cols x 128 k,
//     streams Wt_hh[k][n] coalesced float4 (Wt_hh L2-resident, shared by
//     the 8 WGs of each XCD)
//   combine: thread j: gh sum + gi = Gemb[b,t] + sum_l alpha[l]*P[b,l,:],
//     GRU update, h[j] in LDS, write Hbuf.
// LDS 31.5 KB. No enc/W_ih access in the scan at all (P-trick).
// ---------------------------------------------------------------------------
__global__ __launch_bounds__(512) void scan_persist(
    const float* __restrict__ att1,   // [64*49][256]
    const float* __restrict__ W_daT,  // [256][512]
    const float* __restrict__ b_da,   // [256]
    const float* __restrict__ W_fa,   // [256]
    const float* __restrict__ b_fa,   // [1]
    const float* __restrict__ Wt_hh,  // [512][1536]
    const float* __restrict__ b_hh,   // [1536]
    const float* __restrict__ Gemb,   // [3200][1536] (includes b_ih)
    const float* __restrict__ P,      // [3136][1536] = enc @ W_ihc^T
    float* __restrict__ Hbuf)         // [3200][512]
{
    __shared__ float sh_h[512];
    __shared__ float sh_att2[256];
    __shared__ float sh_part[512];
    __shared__ float sh_red[392];
    __shared__ float sh_alpha[64];
    __shared__ float sh_gp[4][1536];

    const int tid = threadIdx.x;
    const int b = blockIdx.x;

    sh_h[tid] = 0.f;
    __syncthreads();

    const float* att1b = att1 + (size_t)b * 49 * 256;
    const float* Pb    = P    + (size_t)b * 49 * 1536;
    const float* Gb    = Gemb + (size_t)b * 50 * 1536;
    float*       Hb    = Hbuf + (size_t)b * 50 * 512;

    const int j2 = tid >> 1, kh = tid & 1;     // att2 assignment
    const int jq = tid & 127, kq = tid >> 7;   // gates assignment
    const float bh0 = b_hh[tid];
    const float bh1 = b_hh[512 + tid];
    const float bh2 = b_hh[1024 + tid];

    for (int t = 0; t < 50; ++t) {
        // ---- att2 partials
        {
            const float4* w4 = (const float4*)(W_daT + (size_t)j2 * 512 + kh * 256);
            const float* hh = sh_h + kh * 256;
            float a = 0.f;
            #pragma unroll 8
            for (int k4 = 0; k4 < 64; ++k4) {
                const float4 w = w4[k4];
                const float4 x = *(const float4*)(hh + k4 * 4);
                a = fmaf(x.x, w.x, a); a = fmaf(x.y, w.y, a);
                a = fmaf(x.z, w.z, a); a = fmaf(x.w, w.w, a);
            }
            sh_part[tid] = a;
        }
        __syncthreads();
        if (tid < 256)
            sh_att2[tid] = sh_part[2 * tid] + sh_part[2 * tid + 1] + b_da[tid];
        __syncthreads();
        // ---- scores: 49 l x 8 chunks of 32 att-dims
        if (tid < 392) {
            const int l = tid >> 3, ch = tid & 7;
            const float4* a4 = (const float4*)(att1b + l * 256 + ch * 32);
            const float* at2 = sh_att2 + ch * 32;
            const float* wf = W_fa + ch * 32;
            float s = 0.f;
            #pragma unroll
            for (int i = 0; i < 8; ++i) {
                const float4 v = a4[i];
                s += my_tanh(v.x + at2[i * 4 + 0]) * wf[i * 4 + 0];
                s += my_tanh(v.y + at2[i * 4 + 1]) * wf[i * 4 + 1];
                s += my_tanh(v.z + at2[i * 4 + 2]) * wf[i * 4 + 2];
                s += my_tanh(v.w + at2[i * 4 + 3]) * wf[i * 4 + 3];
            }
            sh_red[tid] = s;
        }
        __syncthreads();
        // ---- softmax over L=49 on wave 0
        if (tid < 64) {
            float v = -1e30f;
            if (tid < 49) {
                const float* r = sh_red + tid * 8;
                v = r[0] + r[1] + r[2] + r[3] + r[4] + r[5] + r[6] + r[7] + b_fa[0];
            }
            float m = v;
            #pragma unroll
            for (int o = 32; o; o >>= 1) m = fmaxf(m, __shfl_xor(m, o));
            const float e = (tid < 49) ? __expf(v - m) : 0.f;
            float su = e;
            #pragma unroll
            for (int o = 32; o; o >>= 1) su += __shfl_xor(su, o);
            sh_alpha[tid] = e / su;
        }
        __syncthreads();
        // ---- gh partials: 12 cols x 128 k per thread, coalesced Wt_hh stream
        {
            float4 a0 = {0.f,0.f,0.f,0.f}, a1 = {0.f,0.f,0.f,0.f},
                   a2 = {0.f,0.f,0.f,0.f};
            const float* wbase = Wt_hh + (size_t)(kq * 128) * 1536 + jq * 4;
            const float* hk = sh_h + kq * 128;
            #pragma unroll 8
            for (int k = 0; k < 128; ++k) {
                const float hv = hk[k];
                const float4 w0 = *(const float4*)(wbase + (size_t)k * 1536);
                const float4 w1 = *(const float4*)(wbase + (size_t)k * 1536 + 512);
                const float4 w2 = *(const float4*)(wbase + (size_t)k * 1536 + 1024);
                a0.x = fmaf(hv, w0.x, a0.x); a0.y = fmaf(hv, w0.y, a0.y);
                a0.z = fmaf(hv, w0.z, a0.z); a0.w = fmaf(hv, w0.w, a0.w);
                a1.x = fmaf(hv, w1.x, a1.x); a1.y = fmaf(hv, w1.y, a1.y);
                a1.z = fmaf(hv, w1.z, a1.z); a1.w = fmaf(hv, w1.w, a1.w);
                a2.x = fmaf(hv, w2.x, a2.x); a2.y = fmaf(hv, w2.y, a2.y);
                a2.z = fmaf(hv, w2.z, a2.z); a2.w = fmaf(hv, w2.w, a2.w);
            }
            *(float4*)&sh_gp[kq][jq * 4]        = a0;
            *(float4*)&sh_gp[kq][512 + jq * 4]  = a1;
            *(float4*)&sh_gp[kq][1024 + jq * 4] = a2;
        }
        __syncthreads();
        // ---- combine + gi (Gemb + alpha.P) + GRU update (thread = hidden j)
        {
            const int j = tid;
            const float ghr = sh_gp[0][j] + sh_gp[1][j]
                            + sh_gp[2][j] + sh_gp[3][j] + bh0;
            const float ghz = sh_gp[0][512 + j] + sh_gp[1][512 + j]
                            + sh_gp[2][512 + j] + sh_gp[3][512 + j] + bh1;
            const float ghn = sh_gp[0][1024 + j] + sh_gp[1][1024 + j]
                            + sh_gp[2][1024 + j] + sh_gp[3][1024 + j] + bh2;
            const float* g = Gb + (size_t)t * 1536;
            float gir = g[j], giz = g[512 + j], gin = g[1024 + j];
            const float* pp = Pb + j;
            #pragma unroll 7
            for (int l = 0; l < 49; ++l) {
                const float al = sh_alpha[l];
                gir = fmaf(al, pp[(size_t)l * 1536],        gir);
                giz = fmaf(al, pp[(size_t)l * 1536 + 512],  giz);
                gin = fmaf(al, pp[(size_t)l * 1536 + 1024], gin);
            }
            const float r  = my_sigmoid(gir + ghr);
            const float z  = my_sigmoid(giz + ghz);
            const float nn = my_tanh(gin + r * ghn);
            const float hnew = (1.f - z) * nn + z * sh_h[j];
            sh_h[j] = hnew;
            Hb[(size_t)t * 512 + j] = hnew;
        }
        __syncthreads();
    }
}

// ---------------------------------------------------------------------------
extern "C" void kernel_launch(void* const* d_in, const int* in_sizes, int n_in,
                              void* d_out, int out_size, void* d_ws, size_t ws_size,
                              hipStream_t stream) {
    const float* spatial = (const float*)d_in[0];
    const int*   captions= (const int*)d_in[1];
    const float* W_feat  = (const float*)d_in[2];
    const float* b_feat  = (const float*)d_in[3];
    const float* W_ea    = (const float*)d_in[4];
    const float* b_ea    = (const float*)d_in[5];
    const float* W_da    = (const float*)d_in[6];
    const float* b_da    = (const float*)d_in[7];
    const float* W_fa    = (const float*)d_in[8];
    const float* b_fa    = (const float*)d_in[9];
    const float* emb     = (const float*)d_in[10];
    const float* W_ih    = (const float*)d_in[11];
    const float* W_hh    = (const float*)d_in[12];
    const float* b_ih    = (const float*)d_in[13];
    const float* b_hh    = (const float*)d_in[14];
    const float* W_fc    = (const float*)d_in[15];
    const float* b_fc    = (const float*)d_in[16];
    float* out = (float*)d_out;

    // Workspace 26.1 MB. Gemb (19.7 MB) and P (19.3 MB) live in d_out
    // (128 MB) as scratch: both are dead before the fc GEMM overwrites out.
    // Embt aliases Hbuf (consumed by the Gemb GEMM before scan writes Hbuf).
    char* ws = (char*)d_ws;
    float* Wt_ih = (float*)ws; ws += (size_t)1024 * 1536 * 4;   //  6,291,456
    float* W_daT = (float*)ws; ws += (size_t)256 * 512 * 4;     //    524,288
    float* Wt_hh = (float*)ws; ws += (size_t)512 * 1536 * 4;    //  3,145,728
    float* enc   = (float*)ws; ws += (size_t)3136 * 512 * 4;    //  6,422,528
    float* att1  = (float*)ws; ws += (size_t)3136 * 256 * 4;    //  3,211,264
    float* Hbuf  = (float*)ws; ws += (size_t)3200 * 512 * 4;    //  6,553,600
    const size_t NEED = 6291456ull + 524288 + 3145728 + 6422528 + 3211264
                      + 6553600;
    if (ws_size < NEED) return;

    float* Gemb = out;                          // [3200][1536] 19.66 MB
    float* P    = out + (size_t)3200 * 1536;    // [3136][1536] 19.27 MB
    float* Embt = Hbuf;

    dim3 blk(256);
    // Wt_ih[1024][1536] = W_ih^T  (rows 0..511 = emb part, 512.. = ctx part)
    transpose_f32<<<dim3(32, 48), blk, 0, stream>>>(W_ih, Wt_ih, 1536, 1024, 1024);
    // W_daT[256][512] = W_da^T
    transpose_f32<<<dim3(8, 16), blk, 0, stream>>>(W_da, W_daT, 512, 256, 256);
    // Wt_hh[512][1536] = W_hh^T
    transpose_f32<<<dim3(16, 48), blk, 0, stream>>>(W_hh, Wt_hh, 1536, 512, 512);

    // Embt[m,:] = emb[captions[m],:]          [3200,512]
    gather_emb<<<dim3(3200), blk, 0, stream>>>(captions, emb, Embt);

    // enc = spatial @ W_feat + b_feat         [3136,512]
    gemm2_f32<<<dim3(1, 196), blk, 0, stream>>>(spatial, 2048, W_feat, 512, b_feat,
                                                enc, 512, 3136, 512, 2048);
    // att1 = enc @ W_ea + b_ea                [3136,256]
    gemm_f32<<<dim3(1, 196), blk, 0, stream>>>(enc, 512, W_ea, 256, b_ea,
                                               att1, 256, 3136, 256, 512);
    // Gemb = Embt @ Wt_ih[0:512,:] + b_ih     [3200,1536]
    gemm_tile_f32<<<dim3(12, 25), blk, 0, stream>>>(Embt, 512, Wt_ih, 1536, b_ih,
                                                    Gemb, 1536, 3200, 1536, 512);
    // P = enc @ Wt_ih[512:1024,:]             [3136,1536]  (no bias)
    gemm_tile_f32<<<dim3(12, 25), blk, 0, stream>>>(
        enc, 512, Wt_ih + (size_t)512 * 1536, 1536, (const float*)nullptr,
        P, 1536, 3136, 1536, 512);

    // recurrent scan: ONE plain launch, one WG per batch, zero global syncs
    scan_persist<<<dim3(64), dim3(512), 0, stream>>>(
        att1, W_daT, b_da, W_fa, b_fa, Wt_hh, b_hh, Gemb, P, Hbuf);

    // logits = Hbuf @ W_fc + b_fc -> d_out    [3200,10000]
    gemm_tile_f32<<<dim3(79, 25), blk, 0, stream>>>(Hbuf, 512, W_fc, 10000, b_fc,
                                                    out, 10000, 3200, 10000, 512);
}

// Round 6
// 2940.658 us; speedup vs baseline: 2.2877x; 1.5366x over previous
//
#include <hip/hip_runtime.h>

// fp32 everywhere (reference is jnp.float32); captions int32.
//
// Round 6 = round 5 resubmitted: the round-5 bench died with an
// infrastructure error ("MI355X container failed twice") before producing
// any kernel verdict. Audit found no OOB / fault hazard (d_out scratch
// aliasing bounds-checked and proven in round 4; LDS 34.6 KB; all indices
// bounded; graph-capture-safe). Theory unchanged:
// round-4 persistent scan (64 WGs) was latency-starved (VALUBusy 3%,
// per-XCD working set 6.3 MB > 4 MB L2). This round: ONE fused kernel per
// step, 256 WGs = 64 batches x 4 j-slices. With gi = Gemb + alpha*P
// (P-trick), gates WGs recompute attention locally (131K MACs, 4x
// duplicated - cheap), so a step has zero cross-WG deps; h crosses steps
// at the kernel boundary (round-2's proven-cheap sync). Per-WG streams
// drop 4x (Wt_hh slice 786KB + P slice 75KB), all 256 CUs engaged.

static __device__ __forceinline__ float my_tanh(float x) {
    x = fminf(fmaxf(x, -15.f), 15.f);
    float e = __expf(2.f * x);
    return (e - 1.f) / (e + 1.f);
}
static __device__ __forceinline__ float my_sigmoid(float x) {
    return 1.f / (1.f + __expf(-x));
}

// ---------------------------------------------------------------------------
// Tiled fp32 transpose: out[c*R + r] = in[r*ld_in + c]   (out shape [C][R])
// ---------------------------------------------------------------------------
__global__ __launch_bounds__(256) void transpose_f32(
    const float* __restrict__ in, float* __restrict__ out,
    int R, int C, int ld_in)
{
    __shared__ float tile[32][33];
    int tc = blockIdx.x * 32;
    int tr = blockIdx.y * 32;
    int tx = threadIdx.x & 31, ty = threadIdx.x >> 5;  // 32 x 8
    #pragma unroll
    for (int i = 0; i < 4; i++) {
        int r = tr + ty + i * 8, c = tc + tx;
        tile[ty + i * 8][tx] = (r < R && c < C) ? in[(long)r * ld_in + c] : 0.f;
    }
    __syncthreads();
    #pragma unroll
    for (int i = 0; i < 4; i++) {
        int c = tc + ty + i * 8, r = tr + tx;
        if (c < C && r < R) out[(long)c * R + r] = tile[tx][ty + i * 8];
    }
}

// ---------------------------------------------------------------------------
// fp32 GEMM, 1 col/thread, 16 rows/block. Used for att1 (N=256).
// ---------------------------------------------------------------------------
__global__ __launch_bounds__(256) void gemm_f32(
    const float* __restrict__ A, int lda,
    const float* __restrict__ B, int ldb,
    const float* __restrict__ bias,
    float* __restrict__ C, int ldc,
    int M, int N, int K)
{
    __shared__ float Asm[16 * 512];
    const int tid = threadIdx.x;
    const int n = blockIdx.x * 256 + tid;
    const bool active = n < N;
    const int nn = active ? n : (N - 1);
    const int m0 = blockIdx.y * 16;

    float acc[16];
    #pragma unroll
    for (int i = 0; i < 16; i++) acc[i] = 0.f;

    for (int kt = 0; kt < K; kt += 512) {
        for (int idx = tid; idx < 16 * 512; idx += 256) {
            int i = idx >> 9, kk = idx & 511;
            Asm[idx] = A[(long)(m0 + i) * lda + kt + kk];
        }
        __syncthreads();
        for (int k0 = 0; k0 < 512; k0 += 4) {
            float4 a4[16];
            #pragma unroll
            for (int i = 0; i < 16; i++)
                a4[i] = *(const float4*)(&Asm[i * 512 + k0]);
            #pragma unroll
            for (int j = 0; j < 4; j++) {
                float bv = B[(long)(kt + k0 + j) * ldb + nn];
                #pragma unroll
                for (int i = 0; i < 16; i++) {
                    float av = (j == 0) ? a4[i].x : (j == 1) ? a4[i].y
                             : (j == 2) ? a4[i].z : a4[i].w;
                    acc[i] = fmaf(av, bv, acc[i]);
                }
            }
        }
        __syncthreads();
    }

    if (active) {
        float bb = bias ? bias[n] : 0.f;
        #pragma unroll
        for (int i = 0; i < 16; i++)
            C[(long)(m0 + i) * ldc + n] = acc[i] + bb;
    }
}

// ---------------------------------------------------------------------------
// fp32 GEMM, 2 cols/thread, B prefetch pipeline. Used for enc (K=2048).
// ---------------------------------------------------------------------------
__global__ __launch_bounds__(256) void gemm2_f32(
    const float* __restrict__ A, int lda,
    const float* __restrict__ B, int ldb,
    const float* __restrict__ bias,
    float* __restrict__ C, int ldc,
    int M, int N, int K)
{
    __shared__ float Asm[16 * 512];
    const int tid = threadIdx.x;
    const int n0 = blockIdx.x * 512 + tid;
    const int n1 = n0 + 256;
    const bool act0 = n0 < N, act1 = n1 < N;
    const int nn0 = act0 ? n0 : (N - 1);
    const int nn1 = act1 ? n1 : (N - 1);
    const int m0 = blockIdx.y * 16;

    float acc0[16], acc1[16];
    #pragma unroll
    for (int i = 0; i < 16; i++) { acc0[i] = 0.f; acc1[i] = 0.f; }

    for (int kt = 0; kt < K; kt += 512) {
        for (int idx = tid; idx < 16 * 512; idx += 256) {
            int i = idx >> 9, kk = idx & 511;
            Asm[idx] = A[(long)(m0 + i) * lda + kt + kk];
        }
        __syncthreads();

        float bv0[4], bv1[4];
        #pragma unroll
        for (int j = 0; j < 4; ++j) {
            bv0[j] = B[(size_t)(kt + j) * ldb + nn0];
            bv1[j] = B[(size_t)(kt + j) * ldb + nn1];
        }
        for (int k0 = 0; k0 < 512; k0 += 4) {
            float nb0[4], nb1[4];
            if (k0 + 4 < 512) {
                #pragma unroll
                for (int j = 0; j < 4; ++j) {
                    nb0[j] = B[(size_t)(kt + k0 + 4 + j) * ldb + nn0];
                    nb1[j] = B[(size_t)(kt + k0 + 4 + j) * ldb + nn1];
                }
            }
            #pragma unroll
            for (int half = 0; half < 2; ++half) {
                #pragma unroll
                for (int i = 0; i < 8; ++i) {
                    const int row = half * 8 + i;
                    const float4 a = *(const float4*)(&Asm[row * 512 + k0]);
                    acc0[row] = fmaf(a.x, bv0[0], acc0[row]);
                    acc0[row] = fmaf(a.y, bv0[1], acc0[row]);
                    acc0[row] = fmaf(a.z, bv0[2], acc0[row]);
                    acc0[row] = fmaf(a.w, bv0[3], acc0[row]);
                    acc1[row] = fmaf(a.x, bv1[0], acc1[row]);
                    acc1[row] = fmaf(a.y, bv1[1], acc1[row]);
                    acc1[row] = fmaf(a.z, bv1[2], acc1[row]);
                    acc1[row] = fmaf(a.w, bv1[3], acc1[row]);
                }
            }
            #pragma unroll
            for (int j = 0; j < 4; ++j) { bv0[j] = nb0[j]; bv1[j] = nb1[j]; }
        }
        __syncthreads();
    }

    if (act0) {
        const float bb = bias ? bias[n0] : 0.f;
        #pragma unroll
        for (int i = 0; i < 16; i++)
            C[(long)(m0 + i) * ldc + n0] = acc0[i] + bb;
    }
    if (act1) {
        const float bb = bias ? bias[n1] : 0.f;
        #pragma unroll
        for (int i = 0; i < 16; i++)
            C[(long)(m0 + i) * ldc + n1] = acc1[i] + bb;
    }
}

// ---------------------------------------------------------------------------
// Register-blocked fp32 GEMM: 128x128 C-tile, K-tiles of 16, 256 threads,
// 8x8 outputs/thread. Used for Gemb, P, fc. Requires K%16==0, N%4==0.
// ---------------------------------------------------------------------------
__global__ __launch_bounds__(256) void gemm_tile_f32(
    const float* __restrict__ A, int lda,
    const float* __restrict__ B, int ldb,
    const float* __restrict__ bias,
    float* __restrict__ C, int ldc,
    int M, int N, int K)
{
    __shared__ float As[16 * 132];
    __shared__ float Bs[16 * 132];
    const int tid = threadIdx.x;
    const int tx = tid & 15, ty = tid >> 4;
    const int rbase = blockIdx.y * 128;
    const int cbase = blockIdx.x * 128;

    float acc8[8][8];
    #pragma unroll
    for (int i = 0; i < 8; ++i)
        #pragma unroll
        for (int j = 0; j < 8; ++j) acc8[i][j] = 0.f;

    for (int kt = 0; kt < K; kt += 16) {
        #pragma unroll
        for (int u = 0; u < 2; ++u) {
            const int f = tid + u * 256;
            const int m = f >> 2, kq = f & 3;
            int row = rbase + m; if (row > M - 1) row = M - 1;
            const float4 v = *(const float4*)(A + (size_t)row * lda + kt + kq * 4);
            As[(kq * 4 + 0) * 132 + m] = v.x;
            As[(kq * 4 + 1) * 132 + m] = v.y;
            As[(kq * 4 + 2) * 132 + m] = v.z;
            As[(kq * 4 + 3) * 132 + m] = v.w;
        }
        #pragma unroll
        for (int u = 0; u < 2; ++u) {
            const int f = tid + u * 256;
            const int krow = f >> 5, nq = f & 31;
            int col = cbase + nq * 4; if (col > N - 4) col = N - 4;
            *(float4*)(&Bs[krow * 132 + nq * 4]) =
                *(const float4*)(B + (size_t)(kt + krow) * ldb + col);
        }
        __syncthreads();
        #pragma unroll
        for (int kk = 0; kk < 16; ++kk) {
            const float4 a0 = *(const float4*)(&As[kk * 132 + ty * 4]);
            const float4 a1 = *(const float4*)(&As[kk * 132 + 64 + ty * 4]);
            const float4 b0 = *(const float4*)(&Bs[kk * 132 + tx * 4]);
            const float4 b1 = *(const float4*)(&Bs[kk * 132 + 64 + tx * 4]);
            const float av[8] = {a0.x,a0.y,a0.z,a0.w,a1.x,a1.y,a1.z,a1.w};
            const float bv[8] = {b0.x,b0.y,b0.z,b0.w,b1.x,b1.y,b1.z,b1.w};
            #pragma unroll
            for (int i = 0; i < 8; ++i)
                #pragma unroll
                for (int j = 0; j < 8; ++j)
                    acc8[i][j] = fmaf(av[i], bv[j], acc8[i][j]);
        }
        __syncthreads();
    }

    float4 b4[2];
    #pragma unroll
    for (int cj = 0; cj < 2; ++cj) {
        const int col = cbase + cj * 64 + tx * 4;
        if (col < N && bias) {
            b4[cj].x = bias[col]; b4[cj].y = bias[col + 1];
            b4[cj].z = bias[col + 2]; b4[cj].w = bias[col + 3];
        } else { b4[cj].x = b4[cj].y = b4[cj].z = b4[cj].w = 0.f; }
    }
    #pragma unroll
    for (int i = 0; i < 8; ++i) {
        const int row = rbase + (i >> 2) * 64 + ty * 4 + (i & 3);
        if (row >= M) continue;
        #pragma unroll
        for (int cj = 0; cj < 2; ++cj) {
            const int col = cbase + cj * 64 + tx * 4;
            if (col >= N) continue;
            float4 o;
            o.x = acc8[i][cj * 4 + 0] + b4[cj].x;
            o.y = acc8[i][cj * 4 + 1] + b4[cj].y;
            o.z = acc8[i][cj * 4 + 2] + b4[cj].z;
            o.w = acc8[i][cj * 4 + 3] + b4[cj].w;
            *(float4*)(C + (size_t)row * ldc + col) = o;
        }
    }
}

// ---------------------------------------------------------------------------
// Gather embedding rows: out[m,:] = emb[caps[m],:]  (m = b*50+t, 3200 rows)
// ---------------------------------------------------------------------------
__global__ __launch_bounds__(256) void gather_emb(
    const int* __restrict__ caps, const float* __restrict__ emb,
    float* __restrict__ out)
{
    const int m = blockIdx.x;
    const int cap = caps[m];
    const float* src = emb + (size_t)cap * 512;
    float* dst = out + (size_t)m * 512;
    dst[threadIdx.x] = src[threadIdx.x];
    dst[threadIdx.x + 256] = src[threadIdx.x + 256];
}

// ---------------------------------------------------------------------------
// One fused decoder step. Grid 256 WGs = (sl 0..3) x (b 0..63), bid = sl*64+b
// so same-b slices are 64 apart -> same XCD (bid%8 preserved) -> att1[b]/P[b]
// L2-shared. 512 threads. Each WG: full attention (att2 duplicated across
// slices - 131K MACs, cheap), then gh for its 384 gate-cols (Wt_hh k-major
// coalesced float4 slice, 786 KB), gi = Gemb + alpha*P (sliced, 75 KB),
// GRU update for j in [sl*128, sl*128+128). h crosses steps via the kernel
// boundary. LDS 34.6 KB.
// ---------------------------------------------------------------------------
__global__ __launch_bounds__(512) void step_fused(
    const int t,
    const float* __restrict__ att1,   // [64*49][256]
    const float* __restrict__ W_daT,  // [256][512]
    const float* __restrict__ b_da,   // [256]
    const float* __restrict__ W_fa,   // [256]
    const float* __restrict__ b_fa,   // [1]
    const float* __restrict__ Wt_hh,  // [512][1536]
    const float* __restrict__ b_hh,   // [1536]
    const float* __restrict__ Gemb,   // [3200][1536] (includes b_ih)
    const float* __restrict__ P,      // [3136][1536] = enc @ W_ihc^T
    float* __restrict__ h_g,          // [64][512]
    float* __restrict__ Hbuf)         // [3200][512]
{
    __shared__ float sh_h[512];
    __shared__ float sh_att2[256];
    __shared__ float sh_part[512];
    __shared__ float sh_red[392];
    __shared__ float sh_alpha[64];
    __shared__ float sh_gp[16 * 384];
    __shared__ float sh_gh[384];
    __shared__ float sh_gi[384];

    const int tid = threadIdx.x;
    const int b  = blockIdx.x & 63;
    const int sl = blockIdx.x >> 6;

    sh_h[tid] = (t == 0) ? 0.f : h_g[(size_t)b * 512 + tid];
    __syncthreads();

    // ---- att2 = h @ W_da + b_da (full 256 cols; j2 = tid>>1, k-half = tid&1)
    {
        const int j2 = tid >> 1, kh = tid & 1;
        const float4* w4 = (const float4*)(W_daT + (size_t)j2 * 512 + kh * 256);
        const float* hh = sh_h + kh * 256;
        float a = 0.f;
        #pragma unroll 8
        for (int k4 = 0; k4 < 64; ++k4) {
            const float4 w = w4[k4];
            const float4 x = *(const float4*)(hh + k4 * 4);
            a = fmaf(x.x, w.x, a); a = fmaf(x.y, w.y, a);
            a = fmaf(x.z, w.z, a); a = fmaf(x.w, w.w, a);
        }
        sh_part[tid] = a;
    }
    __syncthreads();
    if (tid < 256)
        sh_att2[tid] = sh_part[2 * tid] + sh_part[2 * tid + 1] + b_da[tid];
    __syncthreads();

    // ---- scores: 49 l x 8 chunks of 32 att-dims
    if (tid < 392) {
        const int l = tid >> 3, ch = tid & 7;
        const float4* a4 =
            (const float4*)(att1 + ((size_t)b * 49 + l) * 256 + ch * 32);
        const float* at2 = sh_att2 + ch * 32;
        const float* wf = W_fa + ch * 32;
        float s = 0.f;
        #pragma unroll
        for (int i = 0; i < 8; ++i) {
            const float4 v = a4[i];
            s += my_tanh(v.x + at2[i * 4 + 0]) * wf[i * 4 + 0];
            s += my_tanh(v.y + at2[i * 4 + 1]) * wf[i * 4 + 1];
            s += my_tanh(v.z + at2[i * 4 + 2]) * wf[i * 4 + 2];
            s += my_tanh(v.w + at2[i * 4 + 3]) * wf[i * 4 + 3];
        }
        sh_red[tid] = s;
    }
    __syncthreads();

    // ---- softmax over L=49 on wave 0
    if (tid < 64) {
        float v = -1e30f;
        if (tid < 49) {
            const float* r = sh_red + tid * 8;
            v = r[0] + r[1] + r[2] + r[3] + r[4] + r[5] + r[6] + r[7] + b_fa[0];
        }
        float m = v;
        #pragma unroll
        for (int o = 32; o; o >>= 1) m = fmaxf(m, __shfl_xor(m, o));
        const float e = (tid < 49) ? __expf(v - m) : 0.f;
        float su = e;
        #pragma unroll
        for (int o = 32; o; o >>= 1) su += __shfl_xor(su, o);
        sh_alpha[tid] = e / su;
    }
    __syncthreads();

    // ---- gh partials: thread (jq = tid&31, kq = tid>>5); 4 j's (float4),
    //      3 gates, k in [kq*32, kq*32+32); Wt_hh rows coalesced.
    {
        const int jq = tid & 31, kq = tid >> 5;
        const int jbase = sl * 128 + jq * 4;
        const float* wrow = Wt_hh + (size_t)(kq * 32) * 1536 + jbase;
        const float* hk = sh_h + kq * 32;
        float4 a0 = {0.f,0.f,0.f,0.f}, a1 = {0.f,0.f,0.f,0.f},
               a2 = {0.f,0.f,0.f,0.f};
        #pragma unroll 8
        for (int k = 0; k < 32; ++k) {
            const float hv = hk[k];
            const float4 w0 = *(const float4*)(wrow + (size_t)k * 1536);
            const float4 w1 = *(const float4*)(wrow + (size_t)k * 1536 + 512);
            const float4 w2 = *(const float4*)(wrow + (size_t)k * 1536 + 1024);
            a0.x = fmaf(hv, w0.x, a0.x); a0.y = fmaf(hv, w0.y, a0.y);
            a0.z = fmaf(hv, w0.z, a0.z); a0.w = fmaf(hv, w0.w, a0.w);
            a1.x = fmaf(hv, w1.x, a1.x); a1.y = fmaf(hv, w1.y, a1.y);
            a1.z = fmaf(hv, w1.z, a1.z); a1.w = fmaf(hv, w1.w, a1.w);
            a2.x = fmaf(hv, w2.x, a2.x); a2.y = fmaf(hv, w2.y, a2.y);
            a2.z = fmaf(hv, w2.z, a2.z); a2.w = fmaf(hv, w2.w, a2.w);
        }
        float* gp = sh_gp + kq * 384;
        *(float4*)(gp + jq * 4)       = a0;
        *(float4*)(gp + 128 + jq * 4) = a1;
        *(float4*)(gp + 256 + jq * 4) = a2;
    }
    __syncthreads();

    // ---- reduce gh partials + bias; gi = Gemb + alpha.P (thread = gate-col)
    if (tid < 384) {
        const int g = tid >> 7, jj = tid & 127;
        const int n = g * 512 + sl * 128 + jj;
        float s = 0.f;
        #pragma unroll
        for (int kq = 0; kq < 16; ++kq) s += sh_gp[kq * 384 + tid];
        sh_gh[tid] = s + b_hh[n];

        float gi = Gemb[((size_t)b * 50 + t) * 1536 + n];
        const float* pp = P + (size_t)b * 49 * 1536 + n;
        #pragma unroll 7
        for (int l = 0; l < 49; ++l)
            gi = fmaf(sh_alpha[l], pp[(size_t)l * 1536], gi);
        sh_gi[tid] = gi;
    }
    __syncthreads();

    // ---- GRU update for this slice's 128 j's
    if (tid < 128) {
        const int j = sl * 128 + tid;
        const float r  = my_sigmoid(sh_gi[tid] + sh_gh[tid]);
        const float z  = my_sigmoid(sh_gi[128 + tid] + sh_gh[128 + tid]);
        const float nn = my_tanh(sh_gi[256 + tid] + r * sh_gh[256 + tid]);
        const float hnew = (1.f - z) * nn + z * sh_h[j];
        h_g[(size_t)b * 512 + j] = hnew;
        Hbuf[((size_t)b * 50 + t) * 512 + j] = hnew;
    }
}

// ---------------------------------------------------------------------------
extern "C" void kernel_launch(void* const* d_in, const int* in_sizes, int n_in,
                              void* d_out, int out_size, void* d_ws, size_t ws_size,
                              hipStream_t stream) {
    const float* spatial = (const float*)d_in[0];
    const int*   captions= (const int*)d_in[1];
    const float* W_feat  = (const float*)d_in[2];
    const float* b_feat  = (const float*)d_in[3];
    const float* W_ea    = (const float*)d_in[4];
    const float* b_ea    = (const float*)d_in[5];
    const float* W_da    = (const float*)d_in[6];
    const float* b_da    = (const float*)d_in[7];
    const float* W_fa    = (const float*)d_in[8];
    const float* b_fa    = (const float*)d_in[9];
    const float* emb     = (const float*)d_in[10];
    const float* W_ih    = (const float*)d_in[11];
    const float* W_hh    = (const float*)d_in[12];
    const float* b_ih    = (const float*)d_in[13];
    const float* b_hh    = (const float*)d_in[14];
    const float* W_fc    = (const float*)d_in[15];
    const float* b_fc    = (const float*)d_in[16];
    float* out = (float*)d_out;

    // Workspace 26.2 MB. Gemb (19.7 MB) and P (19.3 MB) live in d_out
    // (128 MB) as scratch: both are dead before the fc GEMM overwrites out.
    // Embt aliases Hbuf (consumed by the Gemb GEMM before scan writes Hbuf).
    char* ws = (char*)d_ws;
    float* Wt_ih = (float*)ws; ws += (size_t)1024 * 1536 * 4;   //  6,291,456
    float* W_daT = (float*)ws; ws += (size_t)256 * 512 * 4;     //    524,288
    float* Wt_hh = (float*)ws; ws += (size_t)512 * 1536 * 4;    //  3,145,728
    float* enc   = (float*)ws; ws += (size_t)3136 * 512 * 4;    //  6,422,528
    float* att1  = (float*)ws; ws += (size_t)3136 * 256 * 4;    //  3,211,264
    float* Hbuf  = (float*)ws; ws += (size_t)3200 * 512 * 4;    //  6,553,600
    float* h_g   = (float*)ws; ws += (size_t)64 * 512 * 4;      //    131,072
    const size_t NEED = 6291456ull + 524288 + 3145728 + 6422528 + 3211264
                      + 6553600 + 131072;
    if (ws_size < NEED) return;

    float* Gemb = out;                          // [3200][1536] 19.66 MB
    float* P    = out + (size_t)3200 * 1536;    // [3136][1536] 19.27 MB
    float* Embt = Hbuf;

    dim3 blk(256);
    // Wt_ih[1024][1536] = W_ih^T  (rows 0..511 = emb part, 512.. = ctx part)
    transpose_f32<<<dim3(32, 48), blk, 0, stream>>>(W_ih, Wt_ih, 1536, 1024, 1024);
    // W_daT[256][512] = W_da^T
    transpose_f32<<<dim3(8, 16), blk, 0, stream>>>(W_da, W_daT, 512, 256, 256);
    // Wt_hh[512][1536] = W_hh^T
    transpose_f32<<<dim3(16, 48), blk, 0, stream>>>(W_hh, Wt_hh, 1536, 512, 512);

    // Embt[m,:] = emb[captions[m],:]          [3200,512]
    gather_emb<<<dim3(3200), blk, 0, stream>>>(captions, emb, Embt);

    // enc = spatial @ W_feat + b_feat         [3136,512]
    gemm2_f32<<<dim3(1, 196), blk, 0, stream>>>(spatial, 2048, W_feat, 512, b_feat,
                                                enc, 512, 3136, 512, 2048);
    // att1 = enc @ W_ea + b_ea                [3136,256]
    gemm_f32<<<dim3(1, 196), blk, 0, stream>>>(enc, 512, W_ea, 256, b_ea,
                                               att1, 256, 3136, 256, 512);
    // Gemb = Embt @ Wt_ih[0:512,:] + b_ih     [3200,1536]
    gemm_tile_f32<<<dim3(12, 25), blk, 0, stream>>>(Embt, 512, Wt_ih, 1536, b_ih,
                                                    Gemb, 1536, 3200, 1536, 512);
    // P = enc @ Wt_ih[512:1024,:]             [3136,1536]  (no bias)
    gemm_tile_f32<<<dim3(12, 25), blk, 0, stream>>>(
        enc, 512, Wt_ih + (size_t)512 * 1536, 1536, (const float*)nullptr,
        P, 1536, 3136, 1536, 512);

    // recurrent scan: one fused kernel per step, 256 WGs (64 b x 4 slices);
    // h crosses steps at the kernel boundary (zero intra-step cross-WG deps)
    for (int t = 0; t < 50; ++t)
        step_fused<<<dim3(256), dim3(512), 0, stream>>>(
            t, att1, W_daT, b_da, W_fa, b_fa, Wt_hh, b_hh, Gemb, P, h_g, Hbuf);

    // logits = Hbuf @ W_fc + b_fc -> d_out    [3200,10000]
    gemm_tile_f32<<<dim3(79, 25), blk, 0, stream>>>(Hbuf, 512, W_fc, 10000, b_fc,
                                                    out, 10000, 3200, 10000, 512);
}

// Round 7
// 2249.726 us; speedup vs baseline: 2.9903x; 1.3071x over previous
//
#include <hip/hip_runtime.h>

// fp32 everywhere (reference is jnp.float32); captions int32.
//
// Round 7: (1) enc + att1 move from the thin 1/2-col-per-thread GEMMs
// (446 + ~150 µs, VALUBusy 19%) to the register-blocked 128x128 tile GEMM.
// (2) step_fused att2 phase re-mapped to the NATURAL k-major W_da[512][256]:
// the old per-thread-owns-a-row pattern made each wave instruction touch 64
// distinct cache lines at 16/128B utilization and thrash L1 (64 lines x 8
// waves > 32KB L1), amplifying att2's L2 traffic ~8x. New map (jq=tid&63 ->
// 4 cols float4, kq=tid>>6 -> 8 k-groups) reads one contiguous 1KB row per
// wave instruction; partials reduced in LDS. W_da transpose dropped.

static __device__ __forceinline__ float my_tanh(float x) {
    x = fminf(fmaxf(x, -15.f), 15.f);
    float e = __expf(2.f * x);
    return (e - 1.f) / (e + 1.f);
}
static __device__ __forceinline__ float my_sigmoid(float x) {
    return 1.f / (1.f + __expf(-x));
}

// ---------------------------------------------------------------------------
// Tiled fp32 transpose: out[c*R + r] = in[r*ld_in + c]   (out shape [C][R])
// ---------------------------------------------------------------------------
__global__ __launch_bounds__(256) void transpose_f32(
    const float* __restrict__ in, float* __restrict__ out,
    int R, int C, int ld_in)
{
    __shared__ float tile[32][33];
    int tc = blockIdx.x * 32;
    int tr = blockIdx.y * 32;
    int tx = threadIdx.x & 31, ty = threadIdx.x >> 5;  // 32 x 8
    #pragma unroll
    for (int i = 0; i < 4; i++) {
        int r = tr + ty + i * 8, c = tc + tx;
        tile[ty + i * 8][tx] = (r < R && c < C) ? in[(long)r * ld_in + c] : 0.f;
    }
    __syncthreads();
    #pragma unroll
    for (int i = 0; i < 4; i++) {
        int c = tc + ty + i * 8, r = tr + tx;
        if (c < C && r < R) out[(long)c * R + r] = tile[tx][ty + i * 8];
    }
}

// ---------------------------------------------------------------------------
// Register-blocked fp32 GEMM: 128x128 C-tile, K-tiles of 16, 256 threads,
// 8x8 outputs/thread. Used for enc, att1, Gemb, P, fc.
// Requires K%16==0, N%4==0, lda%4==0. Row/col edges masked.
// ---------------------------------------------------------------------------
__global__ __launch_bounds__(256) void gemm_tile_f32(
    const float* __restrict__ A, int lda,
    const float* __restrict__ B, int ldb,
    const float* __restrict__ bias,
    float* __restrict__ C, int ldc,
    int M, int N, int K)
{
    __shared__ float As[16 * 132];
    __shared__ float Bs[16 * 132];
    const int tid = threadIdx.x;
    const int tx = tid & 15, ty = tid >> 4;
    const int rbase = blockIdx.y * 128;
    const int cbase = blockIdx.x * 128;

    float acc8[8][8];
    #pragma unroll
    for (int i = 0; i < 8; ++i)
        #pragma unroll
        for (int j = 0; j < 8; ++j) acc8[i][j] = 0.f;

    for (int kt = 0; kt < K; kt += 16) {
        #pragma unroll
        for (int u = 0; u < 2; ++u) {
            const int f = tid + u * 256;
            const int m = f >> 2, kq = f & 3;
            int row = rbase + m; if (row > M - 1) row = M - 1;
            const float4 v = *(const float4*)(A + (size_t)row * lda + kt + kq * 4);
            As[(kq * 4 + 0) * 132 + m] = v.x;
            As[(kq * 4 + 1) * 132 + m] = v.y;
            As[(kq * 4 + 2) * 132 + m] = v.z;
            As[(kq * 4 + 3) * 132 + m] = v.w;
        }
        #pragma unroll
        for (int u = 0; u < 2; ++u) {
            const int f = tid + u * 256;
            const int krow = f >> 5, nq = f & 31;
            int col = cbase + nq * 4; if (col > N - 4) col = N - 4;
            *(float4*)(&Bs[krow * 132 + nq * 4]) =
                *(const float4*)(B + (size_t)(kt + krow) * ldb + col);
        }
        __syncthreads();
        #pragma unroll
        for (int kk = 0; kk < 16; ++kk) {
            const float4 a0 = *(const float4*)(&As[kk * 132 + ty * 4]);
            const float4 a1 = *(const float4*)(&As[kk * 132 + 64 + ty * 4]);
            const float4 b0 = *(const float4*)(&Bs[kk * 132 + tx * 4]);
            const float4 b1 = *(const float4*)(&Bs[kk * 132 + 64 + tx * 4]);
            const float av[8] = {a0.x,a0.y,a0.z,a0.w,a1.x,a1.y,a1.z,a1.w};
            const float bv[8] = {b0.x,b0.y,b0.z,b0.w,b1.x,b1.y,b1.z,b1.w};
            #pragma unroll
            for (int i = 0; i < 8; ++i)
                #pragma unroll
                for (int j = 0; j < 8; ++j)
                    acc8[i][j] = fmaf(av[i], bv[j], acc8[i][j]);
        }
        __syncthreads();
    }

    float4 b4[2];
    #pragma unroll
    for (int cj = 0; cj < 2; ++cj) {
        const int col = cbase + cj * 64 + tx * 4;
        if (col < N && bias) {
            b4[cj].x = bias[col]; b4[cj].y = bias[col + 1];
            b4[cj].z = bias[col + 2]; b4[cj].w = bias[col + 3];
        } else { b4[cj].x = b4[cj].y = b4[cj].z = b4[cj].w = 0.f; }
    }
    #pragma unroll
    for (int i = 0; i < 8; ++i) {
        const int row = rbase + (i >> 2) * 64 + ty * 4 + (i & 3);
        if (row >= M) continue;
        #pragma unroll
        for (int cj = 0; cj < 2; ++cj) {
            const int col = cbase + cj * 64 + tx * 4;
            if (col >= N) continue;
            float4 o;
            o.x = acc8[i][cj * 4 + 0] + b4[cj].x;
            o.y = acc8[i][cj * 4 + 1] + b4[cj].y;
            o.z = acc8[i][cj * 4 + 2] + b4[cj].z;
            o.w = acc8[i][cj * 4 + 3] + b4[cj].w;
            *(float4*)(C + (size_t)row * ldc + col) = o;
        }
    }
}

// ---------------------------------------------------------------------------
// Gather embedding rows: out[m,:] = emb[caps[m],:]  (m = b*50+t, 3200 rows)
// ---------------------------------------------------------------------------
__global__ __launch_bounds__(256) void gather_emb(
    const int* __restrict__ caps, const float* __restrict__ emb,
    float* __restrict__ out)
{
    const int m = blockIdx.x;
    const int cap = caps[m];
    const float* src = emb + (size_t)cap * 512;
    float* dst = out + (size_t)m * 512;
    dst[threadIdx.x] = src[threadIdx.x];
    dst[threadIdx.x + 256] = src[threadIdx.x + 256];
}

// ---------------------------------------------------------------------------
// One fused decoder step. Grid 256 WGs = (sl 0..3) x (b 0..63), 512 threads.
// Each WG: full attention (att2 via NATURAL k-major W_da, coalesced 1KB-row
// wave reads, 8-way k-split partials in LDS), then gh for its 384 gate-cols
// (Wt_hh k-major float4 slice), gi = Gemb + alpha*P (sliced), GRU update for
// j in [sl*128, sl*128+128). h crosses steps via the kernel boundary.
// LDS 41 KB.
// ---------------------------------------------------------------------------
__global__ __launch_bounds__(512) void step_fused(
    const int t,
    const float* __restrict__ att1,   // [64*49][256]
    const float* __restrict__ W_da,   // [512][256] natural k-major
    const float* __restrict__ b_da,   // [256]
    const float* __restrict__ W_fa,   // [256]
    const float* __restrict__ b_fa,   // [1]
    const float* __restrict__ Wt_hh,  // [512][1536]
    const float* __restrict__ b_hh,   // [1536]
    const float* __restrict__ Gemb,   // [3200][1536] (includes b_ih)
    const float* __restrict__ P,      // [3136][1536] = enc @ W_ihc^T
    float* __restrict__ h_g,          // [64][512]
    float* __restrict__ Hbuf)         // [3200][512]
{
    __shared__ float sh_h[512];
    __shared__ float sh_a2p[8 * 256];   // att2 partials [kq][j]
    __shared__ float sh_att2[256];
    __shared__ float sh_red[392];
    __shared__ float sh_alpha[64];
    __shared__ float sh_gp[16 * 384];
    __shared__ float sh_gh[384];
    __shared__ float sh_gi[384];

    const int tid = threadIdx.x;
    const int b  = blockIdx.x & 63;
    const int sl = blockIdx.x >> 6;

    sh_h[tid] = (t == 0) ? 0.f : h_g[(size_t)b * 512 + tid];
    __syncthreads();

    // ---- att2 partials: jq = tid&63 (4 cols as float4), kq = tid>>6
    //      (8 k-groups of 64). Wave reads one contiguous 1KB W_da row/instr.
    {
        const int jq = tid & 63, kq = tid >> 6;
        const float4* w4 = (const float4*)(W_da + (size_t)(kq * 64) * 256 + jq * 4);
        const float* hk = sh_h + kq * 64;
        float4 a = {0.f, 0.f, 0.f, 0.f};
        #pragma unroll 8
        for (int k = 0; k < 64; ++k) {
            const float hv = hk[k];
            const float4 w = w4[(size_t)k * 64];   // +256 floats per k
            a.x = fmaf(hv, w.x, a.x); a.y = fmaf(hv, w.y, a.y);
            a.z = fmaf(hv, w.z, a.z); a.w = fmaf(hv, w.w, a.w);
        }
        *(float4*)&sh_a2p[kq * 256 + jq * 4] = a;
    }
    __syncthreads();
    if (tid < 256) {
        float s = b_da[tid];
        #pragma unroll
        for (int kq = 0; kq < 8; ++kq) s += sh_a2p[kq * 256 + tid];
        sh_att2[tid] = s;
    }
    __syncthreads();

    // ---- scores: 49 l x 8 chunks of 32 att-dims
    if (tid < 392) {
        const int l = tid >> 3, ch = tid & 7;
        const float4* a4 =
            (const float4*)(att1 + ((size_t)b * 49 + l) * 256 + ch * 32);
        const float* at2 = sh_att2 + ch * 32;
        const float* wf = W_fa + ch * 32;
        float s = 0.f;
        #pragma unroll
        for (int i = 0; i < 8; ++i) {
            const float4 v = a4[i];
            s += my_tanh(v.x + at2[i * 4 + 0]) * wf[i * 4 + 0];
            s += my_tanh(v.y + at2[i * 4 + 1]) * wf[i * 4 + 1];
            s += my_tanh(v.z + at2[i * 4 + 2]) * wf[i * 4 + 2];
            s += my_tanh(v.w + at2[i * 4 + 3]) * wf[i * 4 + 3];
        }
        sh_red[tid] = s;
    }
    __syncthreads();

    // ---- softmax over L=49 on wave 0
    if (tid < 64) {
        float v = -1e30f;
        if (tid < 49) {
            const float* r = sh_red + tid * 8;
            v = r[0] + r[1] + r[2] + r[3] + r[4] + r[5] + r[6] + r[7] + b_fa[0];
        }
        float m = v;
        #pragma unroll
        for (int o = 32; o; o >>= 1) m = fmaxf(m, __shfl_xor(m, o));
        const float e = (tid < 49) ? __expf(v - m) : 0.f;
        float su = e;
        #pragma unroll
        for (int o = 32; o; o >>= 1) su += __shfl_xor(su, o);
        sh_alpha[tid] = e / su;
    }
    __syncthreads();

    // ---- gh partials: thread (jq = tid&31, kq = tid>>5); 4 j's (float4),
    //      3 gates, k in [kq*32, kq*32+32); Wt_hh rows coalesced.
    {
        const int jq = tid & 31, kq = tid >> 5;
        const int jbase = sl * 128 + jq * 4;
        const float* wrow = Wt_hh + (size_t)(kq * 32) * 1536 + jbase;
        const float* hk = sh_h + kq * 32;
        float4 a0 = {0.f,0.f,0.f,0.f}, a1 = {0.f,0.f,0.f,0.f},
               a2 = {0.f,0.f,0.f,0.f};
        #pragma unroll 8
        for (int k = 0; k < 32; ++k) {
            const float hv = hk[k];
            const float4 w0 = *(const float4*)(wrow + (size_t)k * 1536);
            const float4 w1 = *(const float4*)(wrow + (size_t)k * 1536 + 512);
            const float4 w2 = *(const float4*)(wrow + (size_t)k * 1536 + 1024);
            a0.x = fmaf(hv, w0.x, a0.x); a0.y = fmaf(hv, w0.y, a0.y);
            a0.z = fmaf(hv, w0.z, a0.z); a0.w = fmaf(hv, w0.w, a0.w);
            a1.x = fmaf(hv, w1.x, a1.x); a1.y = fmaf(hv, w1.y, a1.y);
            a1.z = fmaf(hv, w1.z, a1.z); a1.w = fmaf(hv, w1.w, a1.w);
            a2.x = fmaf(hv, w2.x, a2.x); a2.y = fmaf(hv, w2.y, a2.y);
            a2.z = fmaf(hv, w2.z, a2.z); a2.w = fmaf(hv, w2.w, a2.w);
        }
        float* gp = sh_gp + kq * 384;
        *(float4*)(gp + jq * 4)       = a0;
        *(float4*)(gp + 128 + jq * 4) = a1;
        *(float4*)(gp + 256 + jq * 4) = a2;
    }
    __syncthreads();

    // ---- reduce gh partials + bias; gi = Gemb + alpha.P (thread = gate-col)
    if (tid < 384) {
        const int g = tid >> 7, jj = tid & 127;
        const int n = g * 512 + sl * 128 + jj;
        float s = 0.f;
        #pragma unroll
        for (int kq = 0; kq < 16; ++kq) s += sh_gp[kq * 384 + tid];
        sh_gh[tid] = s + b_hh[n];

        float gi = Gemb[((size_t)b * 50 + t) * 1536 + n];
        const float* pp = P + (size_t)b * 49 * 1536 + n;
        #pragma unroll 7
        for (int l = 0; l < 49; ++l)
            gi = fmaf(sh_alpha[l], pp[(size_t)l * 1536], gi);
        sh_gi[tid] = gi;
    }
    __syncthreads();

    // ---- GRU update for this slice's 128 j's
    if (tid < 128) {
        const int j = sl * 128 + tid;
        const float r  = my_sigmoid(sh_gi[tid] + sh_gh[tid]);
        const float z  = my_sigmoid(sh_gi[128 + tid] + sh_gh[128 + tid]);
        const float nn = my_tanh(sh_gi[256 + tid] + r * sh_gh[256 + tid]);
        const float hnew = (1.f - z) * nn + z * sh_h[j];
        h_g[(size_t)b * 512 + j] = hnew;
        Hbuf[((size_t)b * 50 + t) * 512 + j] = hnew;
    }
}

// ---------------------------------------------------------------------------
extern "C" void kernel_launch(void* const* d_in, const int* in_sizes, int n_in,
                              void* d_out, int out_size, void* d_ws, size_t ws_size,
                              hipStream_t stream) {
    const float* spatial = (const float*)d_in[0];
    const int*   captions= (const int*)d_in[1];
    const float* W_feat  = (const float*)d_in[2];
    const float* b_feat  = (const float*)d_in[3];
    const float* W_ea    = (const float*)d_in[4];
    const float* b_ea    = (const float*)d_in[5];
    const float* W_da    = (const float*)d_in[6];
    const float* b_da    = (const float*)d_in[7];
    const float* W_fa    = (const float*)d_in[8];
    const float* b_fa    = (const float*)d_in[9];
    const float* emb     = (const float*)d_in[10];
    const float* W_ih    = (const float*)d_in[11];
    const float* W_hh    = (const float*)d_in[12];
    const float* b_ih    = (const float*)d_in[13];
    const float* b_hh    = (const float*)d_in[14];
    const float* W_fc    = (const float*)d_in[15];
    const float* b_fc    = (const float*)d_in[16];
    float* out = (float*)d_out;

    // Workspace 25.7 MB. Gemb (19.7 MB) and P (19.3 MB) live in d_out
    // (128 MB) as scratch: both dead before the fc GEMM overwrites out.
    // Embt aliases Hbuf (consumed by the Gemb GEMM before scan writes Hbuf).
    char* ws = (char*)d_ws;
    float* Wt_ih = (float*)ws; ws += (size_t)1024 * 1536 * 4;   //  6,291,456
    float* Wt_hh = (float*)ws; ws += (size_t)512 * 1536 * 4;    //  3,145,728
    float* enc   = (float*)ws; ws += (size_t)3136 * 512 * 4;    //  6,422,528
    float* att1  = (float*)ws; ws += (size_t)3136 * 256 * 4;    //  3,211,264
    float* Hbuf  = (float*)ws; ws += (size_t)3200 * 512 * 4;    //  6,553,600
    float* h_g   = (float*)ws; ws += (size_t)64 * 512 * 4;      //    131,072
    const size_t NEED = 6291456ull + 3145728 + 6422528 + 3211264
                      + 6553600 + 131072;
    if (ws_size < NEED) return;

    float* Gemb = out;                          // [3200][1536] 19.66 MB
    float* P    = out + (size_t)3200 * 1536;    // [3136][1536] 19.27 MB
    float* Embt = Hbuf;

    dim3 blk(256);
    // Wt_ih[1024][1536] = W_ih^T  (rows 0..511 = emb part, 512.. = ctx part)
    transpose_f32<<<dim3(32, 48), blk, 0, stream>>>(W_ih, Wt_ih, 1536, 1024, 1024);
    // Wt_hh[512][1536] = W_hh^T
    transpose_f32<<<dim3(16, 48), blk, 0, stream>>>(W_hh, Wt_hh, 1536, 512, 512);

    // Embt[m,:] = emb[captions[m],:]          [3200,512]
    gather_emb<<<dim3(3200), blk, 0, stream>>>(captions, emb, Embt);

    // enc = spatial @ W_feat + b_feat         [3136,512]
    gemm_tile_f32<<<dim3(4, 25), blk, 0, stream>>>(spatial, 2048, W_feat, 512,
                                                   b_feat, enc, 512,
                                                   3136, 512, 2048);
    // att1 = enc @ W_ea + b_ea                [3136,256]
    gemm_tile_f32<<<dim3(2, 25), blk, 0, stream>>>(enc, 512, W_ea, 256, b_ea,
                                                   att1, 256, 3136, 256, 512);
    // Gemb = Embt @ Wt_ih[0:512,:] + b_ih     [3200,1536]
    gemm_tile_f32<<<dim3(12, 25), blk, 0, stream>>>(Embt, 512, Wt_ih, 1536, b_ih,
                                                    Gemb, 1536, 3200, 1536, 512);
    // P = enc @ Wt_ih[512:1024,:]             [3136,1536]  (no bias)
    gemm_tile_f32<<<dim3(12, 25), blk, 0, stream>>>(
        enc, 512, Wt_ih + (size_t)512 * 1536, 1536, (const float*)nullptr,
        P, 1536, 3136, 1536, 512);

    // recurrent scan: one fused kernel per step, 256 WGs (64 b x 4 slices);
    // h crosses steps at the kernel boundary (zero intra-step cross-WG deps)
    for (int t = 0; t < 50; ++t)
        step_fused<<<dim3(256), dim3(512), 0, stream>>>(
            t, att1, W_da, b_da, W_fa, b_fa, Wt_hh, b_hh, Gemb, P, h_g, Hbuf);

    // logits = Hbuf @ W_fc + b_fc -> d_out    [3200,10000]
    gemm_tile_f32<<<dim3(79, 25), blk, 0, stream>>>(Hbuf, 512, W_fc, 10000, b_fc,
                                                    out, 10000, 3200, 10000, 512);
}